// Round 16
// baseline (872.773 us; speedup 1.0000x reference)
//
#include <hip/hip_runtime.h>
#include <hip/hip_bf16.h>
#include <math.h>

typedef float f32x4_t __attribute__((ext_vector_type(4)));
typedef float f32x2_t __attribute__((ext_vector_type(2)));
typedef __bf16 bf16x8_t __attribute__((ext_vector_type(8)));

__device__ __forceinline__ float bf2f(unsigned int u){
  union { float f; unsigned int i; } x; x.i = u << 16; return x.f;
}
__device__ __forceinline__ unsigned short f2bf(float f){
  unsigned int x = __float_as_uint(f);
  unsigned int r = (x + 0x7fffu + ((x >> 16) & 1u)) >> 16;
  return (unsigned short)r;
}
__device__ __forceinline__ unsigned int pk2bf(float a, float b){
  return (unsigned int)f2bf(a) | ((unsigned int)f2bf(b) << 16);
}
// LDS unit swizzle: r = row (0..127), 2-bit XOR applied to 16B-unit index
__device__ __forceinline__ int swz4(int r){ return (r ^ (r >> 2) ^ (r >> 4)) & 3; }

// unpack 8 bf16 (uint4) -> 8 floats, scaled
__device__ __forceinline__ void unp8s(uint4 w, float* f, float s){
  f[0] = bf2f(w.x & 0xffffu) * s; f[1] = bf2f(w.x >> 16) * s;
  f[2] = bf2f(w.y & 0xffffu) * s; f[3] = bf2f(w.y >> 16) * s;
  f[4] = bf2f(w.z & 0xffffu) * s; f[5] = bf2f(w.z >> 16) * s;
  f[6] = bf2f(w.w & 0xffffu) * s; f[7] = bf2f(w.w >> 16) * s;
}
// unpack 4 fp8 e4m3 (one u32) -> 4 floats (HW cvt)
__device__ __forceinline__ void unpf8(unsigned int w, float* f){
  f32x2_t lo = __builtin_amdgcn_cvt_pk_f32_fp8(w, false);
  f32x2_t hi = __builtin_amdgcn_cvt_pk_f32_fp8(w, true);
  f[0] = lo[0]; f[1] = lo[1]; f[2] = hi[0]; f[3] = hi[1];
}
// exact tanh via exp2 (cheap): 1 - 2/(exp2(2*log2e*y)+1)
__device__ __forceinline__ float fast_tanh(float y){
  float e = exp2f(y * 2.8853901817f);
  return 1.0f - 2.0f / (e + 1.0f);
}
// tanh-form gelu (approx to exact-erf gelu, |err| ~1e-3), NaN-free
__device__ __forceinline__ float fast_gelu(float x){
  float x2 = x * x;
  float u = x * fmaf(0.1029527f, x2, 2.3022339f);   // 2*log2e*0.79788456*(1+0.044715*x^2)
  float e = exp2f(u);
  return x - x / (e + 1.0f);
}

#define GLOAD16(gsrc, ldst) \
  __builtin_amdgcn_global_load_lds((const __attribute__((address_space(1))) unsigned int*)(gsrc), \
                                   (__attribute__((address_space(3))) unsigned int*)(ldst), 16, 0, 0)

// ---------------- K-1: zero scratch
__global__ void zero_buf(uint4* __restrict__ p, int n16){
  int i = blockIdx.x * 256 + threadIdx.x;
  if (i < n16) p[i] = make_uint4(0, 0, 0, 0);
}

// ---------------- K0: fused prep — pack_weights | pack_wa1 | convert_x | degree_hist,
// then the LAST block to retire performs the exclusive scan (completion counter).
__global__ void prep(const float* __restrict__ x,
                     const float* __restrict__ Wq, const float* __restrict__ Wk,
                     const float* __restrict__ Wv, const float* __restrict__ Ws,
                     const float* __restrict__ bq, const float* __restrict__ bk,
                     const float* __restrict__ bv, const float* __restrict__ bs,
                     const float* __restrict__ Wa1, const int* __restrict__ ei,
                     unsigned short* __restrict__ xbf, unsigned short* __restrict__ wcatT,
                     float* __restrict__ bcat, unsigned short* __restrict__ wa1T,
                     int* __restrict__ deg, int* __restrict__ rowst,
                     unsigned int* __restrict__ pcnt, int n, int ne, int nbcv){
  const int b = blockIdx.x, tid = threadIdx.x;
  if (b < 2048){
    int idx = b * 256 + tid;
    int c = idx >> 9, k = idx & 511;
    int sel = c >> 8, cc = c & 255;
    const float* W = (sel == 0) ? Wq : (sel == 1) ? Wk : (sel == 2) ? Wv : Ws;
    int p = ((k >> 3) & 3) ^ swz4(c & 127);
    int dst = c * 512 + (k & ~31) + p * 8 + (k & 7);
    wcatT[dst] = f2bf(W[k * 256 + cc]);
    if (idx < 1024){
      int sel2 = idx >> 8, cc2 = idx & 255;
      const float* B = (sel2 == 0) ? bq : (sel2 == 1) ? bk : (sel2 == 2) ? bv : bs;
      bcat[idx] = B[cc2];
    }
  } else if (b < 2304){
    int idx = (b - 2048) * 256 + tid;
    int c = idx >> 8, k = idx & 255;
    wa1T[idx] = f2bf(Wa1[k * 256 + c]);
  } else if (b < 2304 + nbcv){
    int idx = (b - 2304) * 256 + tid;
    if (idx < n * 64){
      int node = idx >> 6, un = idx & 63;
      int k0 = (un >> 2) * 32, u = un & 3;
      const float* src = x + (size_t)node * 512 + k0 + u * 8;
      float4 f0 = *reinterpret_cast<const float4*>(src);
      float4 f1 = *reinterpret_cast<const float4*>(src + 4);
      uint4 o;
      o.x = pk2bf(f0.x, f0.y); o.y = pk2bf(f0.z, f0.w);
      o.z = pk2bf(f1.x, f1.y); o.w = pk2bf(f1.z, f1.w);
      int p = u ^ swz4(node & 127);
      *reinterpret_cast<uint4*>(xbf + (size_t)node * 512 + k0 + p * 8) = o;
    }
  } else {
    int i = (b - 2304 - nbcv) * 256 + tid;
    if (i < ne) atomicAdd(&deg[ei[ne + i]], 1);
  }
  // ---- completion counter: last block performs the exclusive scan deg -> rowst ----
  __threadfence();
  __shared__ unsigned int rank_s;
  if (tid == 0) rank_s = atomicAdd(pcnt, 1u);
  __syncthreads();
  if (rank_s != (unsigned int)(gridDim.x - 1)) return;
  __threadfence();
  __shared__ int sm[256];
  int per = (n + 255) >> 8;
  int start = tid * per;
  int sum = 0;
  for (int i = 0; i < per; i++){
    int idx = start + i;
    sum += (idx < n) ? deg[idx] : 0;
  }
  sm[tid] = sum; __syncthreads();
  for (int off = 1; off < 256; off <<= 1){
    int t2 = (tid >= off) ? sm[tid - off] : 0;
    __syncthreads();
    sm[tid] += t2;
    __syncthreads();
  }
  int run = sm[tid] - sum;
  for (int i = 0; i < per; i++){
    int idx = start + i;
    if (idx < n){
      rowst[idx] = run;
      run += deg[idx];
    }
  }
  if (tid == 0) rowst[n] = ne;
}

// ---------------- K3: QKVS GEMM + concurrent edge scatter.
// First nscb blocks scatter edges into CSR (independent, latency-bound — hides under MFMA).
// Remaining blocks: triple-buffered gload_lds GEMM (round-8 proven core), vmcnt(8),
// XCD swizzle, swapped-operand MFMA, bank-uniform LDS-staged epilogue.
__global__ __launch_bounds__(256) void gemm_qkvs(const unsigned short* __restrict__ xbf,
                                                 const unsigned short* __restrict__ wcatT,
                                                 const float* __restrict__ bcat,
                                                 unsigned short* __restrict__ qbf,
                                                 unsigned short* __restrict__ sbf,
                                                 unsigned char* __restrict__ kv8,
                                                 const int* __restrict__ ei,
                                                 const int* __restrict__ rowst,
                                                 int* __restrict__ cursor,
                                                 int* __restrict__ csrsrc,
                                                 int n_nodes, int ne, int mblocks, int nscb){
  __shared__ __align__(16) unsigned char smem[49152];
  const int tid = threadIdx.x;
  if (blockIdx.x < (unsigned)nscb){
    int i = blockIdx.x * 256 + tid;
    if (i < ne){
      int d = ei[ne + i];
      int pos = atomicAdd(&cursor[d], 1);
      csrsrc[rowst[d] + pos] = ei[i] << 9;
    }
    return;
  }
  const int bid = blockIdx.x - nscb;
  const int lane = tid & 63, wave = tid >> 6;
  const int wm = wave >> 1, wn = wave & 1;
  const int g = (bid & 7) * mblocks + (bid >> 3);
  const int m_blk = g >> 3, n_blk = g & 7;
  const int m0 = m_blk * 128, n0 = n_blk * 128;
  const int lrow = lane >> 2;
  const int lcol = (lane & 3) * 8;
  const int rA0 = min(m0 + wave * 16 + lrow, n_nodes - 1);
  const int rA1 = min(m0 + (wave + 4) * 16 + lrow, n_nodes - 1);
  const int rB0 = n0 + wave * 16 + lrow;
  const int rB1 = rB0 + 64;
  const int r = lane & 15, q4 = lane >> 4;
  const unsigned short* aG0 = xbf   + (size_t)rA0 * 512 + lcol;
  const unsigned short* aG1 = xbf   + (size_t)rA1 * 512 + lcol;
  const unsigned short* bG0 = wcatT + (size_t)rB0 * 512 + lcol;
  const unsigned short* bG1 = wcatT + (size_t)rB1 * 512 + lcol;
  int aoff[4], boff[4];
  #pragma unroll
  for (int mi = 0; mi < 4; mi++){ int rr = wm * 64 + mi * 16 + r; aoff[mi] = rr * 32 + ((q4 ^ swz4(rr)) * 8); }
  #pragma unroll
  for (int ni = 0; ni < 4; ni++){ int rb = wn * 64 + ni * 16 + r; boff[ni] = rb * 32 + ((q4 ^ swz4(rb)) * 8); }
  f32x4_t acc[4][4] = {};
#define STAGE(base, k0) { \
    unsigned short* As_ = (unsigned short*)(smem + (base)); \
    unsigned short* Bs_ = (unsigned short*)(smem + (base) + 8192); \
    GLOAD16(aG0 + (k0), &As_[wave * 512]); \
    GLOAD16(aG1 + (k0), &As_[(wave + 4) * 512]); \
    GLOAD16(bG0 + (k0), &Bs_[wave * 512]); \
    GLOAD16(bG1 + (k0), &Bs_[(wave + 4) * 512]); \
  }
  STAGE(0, 0);
  STAGE(16384, 32);
  int cbase = 0;
  int sbase = 32768;
  for (int t = 0; t < 16; t++){
    if (t + 2 < 16){
      STAGE(sbase, (t + 2) * 32);
      asm volatile("s_waitcnt vmcnt(8)" ::: "memory");
    } else if (t + 1 < 16){
      asm volatile("s_waitcnt vmcnt(4)" ::: "memory");
    } else {
      asm volatile("s_waitcnt vmcnt(0)" ::: "memory");
    }
    __builtin_amdgcn_s_barrier();
    asm volatile("" ::: "memory");
    const unsigned short* As = (const unsigned short*)(smem + cbase);
    const unsigned short* Bs = (const unsigned short*)(smem + cbase + 8192);
    bf16x8_t a[4], b[4];
    #pragma unroll
    for (int mi = 0; mi < 4; mi++) a[mi] = *reinterpret_cast<const bf16x8_t*>(&As[aoff[mi]]);
    #pragma unroll
    for (int ni = 0; ni < 4; ni++) b[ni] = *reinterpret_cast<const bf16x8_t*>(&Bs[boff[ni]]);
    #pragma unroll
    for (int mi = 0; mi < 4; mi++)
      #pragma unroll
      for (int ni = 0; ni < 4; ni++)
        acc[mi][ni] = __builtin_amdgcn_mfma_f32_16x16x32_bf16(b[ni], a[mi], acc[mi][ni], 0, 0, 0);
    __builtin_amdgcn_s_barrier();
    asm volatile("" ::: "memory");
    cbase += 16384; if (cbase == 49152) cbase = 0;
    sbase += 16384; if (sbase == 49152) sbase = 0;
  }
#undef STAGE
  const bool isQ = (n_blk < 2), isS = (n_blk >= 6);
  if (isQ || isS){
    unsigned short* St = (unsigned short*)smem;   // [64][152] bf16
    unsigned short* outp = isQ ? qbf : sbf;
    const int colhalf = isQ ? n_blk : (n_blk - 6);
    #pragma unroll
    for (int ch = 0; ch < 2; ch++){
      if (wm == ch){
        #pragma unroll
        for (int mi = 0; mi < 4; mi++){
          #pragma unroll
          for (int ni = 0; ni < 4; ni++){
            int mloc = mi * 16 + r;
            int nl = wn * 64 + ni * 16 + q4 * 4;
            float4 bb = *reinterpret_cast<const float4*>(&bcat[n0 + nl]);
            uint2 w;
            w.x = pk2bf(acc[mi][ni][0] + bb.x, acc[mi][ni][1] + bb.y);
            w.y = pk2bf(acc[mi][ni][2] + bb.z, acc[mi][ni][3] + bb.w);
            *reinterpret_cast<uint2*>(&St[mloc * 152 + nl]) = w;
          }
        }
      }
      __syncthreads();
      #pragma unroll
      for (int it = 0; it < 4; it++){
        int u = it * 256 + tid;
        int row = u >> 4, seg = (u & 15) * 8;
        int node = m0 + ch * 64 + row;
        if (node < n_nodes){
          uint4 v = *reinterpret_cast<const uint4*>(&St[row * 152 + seg]);
          *reinterpret_cast<uint4*>(outp + (size_t)node * 256 + colhalf * 128 + seg) = v;
        }
      }
      __syncthreads();
    }
  } else {
    unsigned char* St8 = smem;                    // [64][144] fp8
    #pragma unroll
    for (int ch = 0; ch < 2; ch++){
      if (wm == ch){
        #pragma unroll
        for (int mi = 0; mi < 4; mi++){
          #pragma unroll
          for (int ni = 0; ni < 4; ni++){
            int mloc = mi * 16 + r;
            int nl = wn * 64 + ni * 16 + q4 * 4;
            float4 bb = *reinterpret_cast<const float4*>(&bcat[n0 + nl]);
            int u = 0;
            u = __builtin_amdgcn_cvt_pk_fp8_f32(acc[mi][ni][0] + bb.x, acc[mi][ni][1] + bb.y, u, false);
            u = __builtin_amdgcn_cvt_pk_fp8_f32(acc[mi][ni][2] + bb.z, acc[mi][ni][3] + bb.w, u, true);
            *reinterpret_cast<unsigned int*>(&St8[mloc * 144 + nl]) = (unsigned int)u;
          }
        }
      }
      __syncthreads();
      #pragma unroll
      for (int it = 0; it < 2; it++){
        int u = it * 256 + tid;
        int row = u >> 3, seg = (u & 7) * 16;
        int node = m0 + ch * 64 + row;
        if (node < n_nodes){
          uint4 v = *reinterpret_cast<const uint4*>(&St8[row * 144 + seg]);
          *reinterpret_cast<uint4*>(kv8 + (size_t)node * 512 + (n_blk - 2) * 128 + seg) = v;
        }
      }
      __syncthreads();
    }
  }
}

// ---------------- K7: per-dst online-softmax aggregation
// fp8 K/V (combined 512B row), 16 lanes/edge, 2 chains/node, 2 nodes/wave,
// pair-processing + pair prefetch per chain, shfl_xor(16) merge, fast gelu.
__global__ __launch_bounds__(256) void edge_attn(const unsigned short* __restrict__ qbf,
                                                 const unsigned short* __restrict__ sbf,
                                                 const unsigned char* __restrict__ kv8,
                                                 const int* __restrict__ rowstart,
                                                 const int* __restrict__ csrsrc,
                                                 unsigned short* __restrict__ hbf, int n_nodes){
  const int tid = threadIdx.x;
  const int lane = tid & 63, wave = tid >> 6;
  const int g = lane >> 4, t = lane & 15;
  const int chain = g & 1;
  const int node = blockIdx.x * 8 + wave * 2 + (g >> 1);
  const bool active = node < n_nodes;
  const int nd = active ? node : 0;
  const float qs = 0.0625f * 1.44269504088896340736f;  // (1/sqrt(256)) * log2(e)
  float q[16];
  {
    const unsigned short* qp = qbf + (size_t)nd * 256 + t * 16;
    uint4 w0 = *reinterpret_cast<const uint4*>(qp);
    uint4 w1 = *reinterpret_cast<const uint4*>(qp + 8);
    unp8s(w0, q, qs); unp8s(w1, q + 8, qs);
  }
  int rs = rowstart[nd];
  int re = active ? rowstart[nd + 1] : rs;
  float m = -1e30f, den = 0.f;
  float acc[16];
  #pragma unroll
  for (int j = 0; j < 16; j++) acc[j] = 0.f;
  const int i0 = rs + chain;
  uint4 kA = make_uint4(0,0,0,0), vA = kA, kB = kA, vB = kA;
  if (i0 < re){
    const unsigned char* p1 = kv8 + (size_t)csrsrc[i0] + t * 16;
    kA = *reinterpret_cast<const uint4*>(p1);
    vA = *reinterpret_cast<const uint4*>(p1 + 256);
    if (i0 + 2 < re){
      const unsigned char* p2 = kv8 + (size_t)csrsrc[i0 + 2] + t * 16;
      kB = *reinterpret_cast<const uint4*>(p2);
      vB = *reinterpret_cast<const uint4*>(p2 + 256);
    }
  }
  for (int i = i0; i < re; i += 4){
    uint4 k1 = kA, v1 = vA, k2 = kB, v2 = vB;
    const bool has2 = (i + 2 < re);
    if (i + 4 < re){
      const unsigned char* p1 = kv8 + (size_t)csrsrc[i + 4] + t * 16;
      kA = *reinterpret_cast<const uint4*>(p1);
      vA = *reinterpret_cast<const uint4*>(p1 + 256);
      if (i + 6 < re){
        const unsigned char* p2 = kv8 + (size_t)csrsrc[i + 6] + t * 16;
        kB = *reinterpret_cast<const uint4*>(p2);
        vB = *reinterpret_cast<const uint4*>(p2 + 256);
      }
    }
    float kf1[16], kf2[16];
    unpf8(k1.x, kf1); unpf8(k1.y, kf1 + 4); unpf8(k1.z, kf1 + 8); unpf8(k1.w, kf1 + 12);
    unpf8(k2.x, kf2); unpf8(k2.y, kf2 + 4); unpf8(k2.z, kf2 + 8); unpf8(k2.w, kf2 + 12);
    float s1 = 0.f, s2 = 0.f;
    #pragma unroll
    for (int j = 0; j < 16; j++){ s1 = fmaf(q[j], kf1[j], s1); s2 = fmaf(q[j], kf2[j], s2); }
    s1 += __shfl_xor(s1, 1); s2 += __shfl_xor(s2, 1);
    s1 += __shfl_xor(s1, 2); s2 += __shfl_xor(s2, 2);
    s1 += __shfl_xor(s1, 4); s2 += __shfl_xor(s2, 4);
    s1 += __shfl_xor(s1, 8); s2 += __shfl_xor(s2, 8);
    if (!has2) s2 = -1e30f;
    float vf1[16], vf2[16];
    unpf8(v1.x, vf1); unpf8(v1.y, vf1 + 4); unpf8(v1.z, vf1 + 8); unpf8(v1.w, vf1 + 12);
    unpf8(v2.x, vf2); unpf8(v2.y, vf2 + 4); unpf8(v2.z, vf2 + 8); unpf8(v2.w, vf2 + 12);
    float mn = fmaxf(m, fmaxf(s1, s2));
    float sc = exp2f(m - mn);
    float e1 = exp2f(s1 - mn);
    float e2 = exp2f(s2 - mn);
    den = den * sc + e1 + e2;
    #pragma unroll
    for (int j = 0; j < 16; j++)
      acc[j] = fmaf(acc[j], sc, fmaf(e1, vf1[j], e2 * vf2[j]));
    m = mn;
  }
  // merge the two chains (lane ^ 16 pairs groups 0<->1, 2<->3)
  {
    float mo  = __shfl_xor(m, 16);
    float dno = __shfl_xor(den, 16);
    float mn  = fmaxf(m, mo);
    float a_  = exp2f(m - mn);
    float b_  = exp2f(mo - mn);
    den = den * a_ + dno * b_;
    #pragma unroll
    for (int j = 0; j < 16; j++){
      float oth = __shfl_xor(acc[j], 16);
      acc[j] = acc[j] * a_ + oth * b_;
    }
  }
  float inv = (den > 0.f) ? 1.f / den : 0.f;
  const unsigned short* sp = sbf + (size_t)nd * 256 + t * 16;
  uint4 s0 = *reinterpret_cast<const uint4*>(sp);
  uint4 s1v = *reinterpret_cast<const uint4*>(sp + 8);
  float sf[16]; unp8s(s0, sf, 1.0f); unp8s(s1v, sf + 8, 1.0f);
  unsigned int o[8];
  #pragma unroll
  for (int j = 0; j < 8; j++){
    float h0 = fast_gelu(acc[2 * j] * inv + sf[2 * j]);
    float h1 = fast_gelu(acc[2 * j + 1] * inv + sf[2 * j + 1]);
    o[j] = (unsigned int)f2bf(h0) | ((unsigned int)f2bf(h1) << 16);
  }
  if (active && chain == 0){
    uint4* dst = reinterpret_cast<uint4*>(hbf + (size_t)node * 256 + t * 16);
    dst[0] = make_uint4(o[0], o[1], o[2], o[3]);
    dst[1] = make_uint4(o[4], o[5], o[6], o[7]);
  }
}

// ---------------- K8: es2[n][2] = exp(tanh(hbf@Wa1 + ba1)@Wa2 + ba2); den_g += block sums
__global__ __launch_bounds__(256) void mlp_mfma(const unsigned short* __restrict__ hbf,
                                                const unsigned short* __restrict__ wa1T,
                                                const float* __restrict__ ba1,
                                                const float* __restrict__ Wa2,
                                                const float* __restrict__ ba2,
                                                float* __restrict__ es2,
                                                float* __restrict__ den_g, int n_nodes){
  __shared__ __align__(16) unsigned short As[64 * 72];
  __shared__ float s2s[64][2];
  const int tid = threadIdx.x;
  const int lane = tid & 63, wave = tid >> 6;
  const int m0 = blockIdx.x * 64;
  const int c0 = wave * 64;
  const int r = lane & 15, rg = (lane >> 4) * 4;
  if (tid < 128) s2s[tid >> 1][tid & 1] = 0.f;
  f32x4_t acc[4][4] = {};
  for (int k0 = 0; k0 < 256; k0 += 64){
    int arow = tid >> 2, akc = (tid & 3) * 16;
    uint4 a0v = make_uint4(0,0,0,0), a1v = make_uint4(0,0,0,0);
    if (m0 + arow < n_nodes){
      const unsigned short* src = hbf + (size_t)(m0 + arow) * 256 + k0 + akc;
      a0v = *reinterpret_cast<const uint4*>(src);
      a1v = *reinterpret_cast<const uint4*>(src + 8);
    }
    *reinterpret_cast<uint4*>(&As[arow * 72 + akc]) = a0v;
    *reinterpret_cast<uint4*>(&As[arow * 72 + akc + 8]) = a1v;
    __syncthreads();
    #pragma unroll
    for (int kk = 0; kk < 2; kk++){
      int kg = kk * 32 + (lane >> 4) * 8;
      bf16x8_t a[4], b[4];
      #pragma unroll
      for (int mi = 0; mi < 4; mi++)
        a[mi] = *reinterpret_cast<const bf16x8_t*>(&As[(mi * 16 + r) * 72 + kg]);
      #pragma unroll
      for (int ni = 0; ni < 4; ni++)
        b[ni] = *reinterpret_cast<const bf16x8_t*>(wa1T + (size_t)(c0 + ni * 16 + r) * 256 + k0 + kg);
      #pragma unroll
      for (int mi = 0; mi < 4; mi++)
        #pragma unroll
        for (int ni = 0; ni < 4; ni++)
          acc[mi][ni] = __builtin_amdgcn_mfma_f32_16x16x32_bf16(a[mi], b[ni], acc[mi][ni], 0, 0, 0);
    }
    __syncthreads();
  }
  float w20[4], w21[4], b1c[4];
  #pragma unroll
  for (int ni = 0; ni < 4; ni++){
    int col = c0 + ni * 16 + r;
    w20[ni] = Wa2[col * 2]; w21[ni] = Wa2[col * 2 + 1]; b1c[ni] = ba1[col];
  }
  #pragma unroll
  for (int mi = 0; mi < 4; mi++){
    #pragma unroll
    for (int j = 0; j < 4; j++){
      float t0 = 0.f, t1 = 0.f;
      #pragma unroll
      for (int ni = 0; ni < 4; ni++){
        float t = fast_tanh(acc[mi][ni][j] + b1c[ni]);
        t0 += t * w20[ni]; t1 += t * w21[ni];
      }
      t0 += __shfl_xor(t0, 1); t0 += __shfl_xor(t0, 2);
      t0 += __shfl_xor(t0, 4); t0 += __shfl_xor(t0, 8);
      t1 += __shfl_xor(t1, 1); t1 += __shfl_xor(t1, 2);
      t1 += __shfl_xor(t1, 4); t1 += __shfl_xor(t1, 8);
      if (r == 0){
        int row = mi * 16 + rg + j;
        atomicAdd(&s2s[row][0], t0);
        atomicAdd(&s2s[row][1], t1);
      }
    }
  }
  __syncthreads();
  if (tid < 128){
    int row = tid >> 1, c = tid & 1;
    int node = m0 + row;
    float e = 0.f;
    if (node < n_nodes){
      e = expf(s2s[row][c] + ba2[c]);
      es2[node * 2 + c] = e;
    }
    float sum = e;
    sum += __shfl_xor(sum, 2);  sum += __shfl_xor(sum, 4);
    sum += __shfl_xor(sum, 8);  sum += __shfl_xor(sum, 16);
    sum += __shfl_xor(sum, 32);
    if ((tid & 63) < 2) atomicAdd(&den_g[c], sum);
  }
}

// ---------------- K10: attn + A output + M accumulation + fused logits (completion counter)
__global__ __launch_bounds__(256) void attn_M(const float* __restrict__ es2, const float* __restrict__ den_g,
                                              const unsigned short* __restrict__ hbf, const int* __restrict__ label,
                                              float* __restrict__ Mbuf, float* __restrict__ outA,
                                              const float* __restrict__ Wc, const float* __restrict__ bc,
                                              float* __restrict__ out, unsigned int* __restrict__ cnt,
                                              int n, int nblocks){
  __shared__ float a0s[256], a1s[256];
  __shared__ float Ms[512];
  __shared__ unsigned int lastrank;
  int tid = threadIdx.x;
  int n0 = blockIdx.x * 256;
  int node = n0 + tid;
  float i0 = 1.f / den_g[0], i1 = 1.f / den_g[1];
  float a0 = 0.f, a1 = 0.f;
  if (node < n){
    a0 = es2[2 * node] * i0;
    a1 = es2[2 * node + 1] * i1;
    outA[node] = (label[0] == 0) ? a0 : a1;
  }
  a0s[tid] = a0; a1s[tid] = a1;
  Ms[tid] = 0.f; Ms[tid + 256] = 0.f;
  __syncthreads();
  const int dgrp = tid & 31;
  const int nl = tid >> 5;
  float M0[8] = {}, M1[8] = {};
  for (int i = nl; i < 256; i += 8){
    int nd = n0 + i;
    if (nd >= n) break;
    uint4 w = *reinterpret_cast<const uint4*>(hbf + (size_t)nd * 256 + dgrp * 8);
    float f[8]; unp8s(w, f, 1.0f);
    float A0 = a0s[i], A1 = a1s[i];
    #pragma unroll
    for (int j = 0; j < 8; j++){
      M0[j] = fmaf(A0, f[j], M0[j]);
      M1[j] = fmaf(A1, f[j], M1[j]);
    }
  }
  #pragma unroll
  for (int j = 0; j < 8; j++){
    M0[j] += __shfl_xor(M0[j], 32);
    M1[j] += __shfl_xor(M1[j], 32);
  }
  if ((tid & 32) == 0){
    #pragma unroll
    for (int j = 0; j < 8; j++){
      atomicAdd(&Ms[dgrp * 8 + j], M0[j]);
      atomicAdd(&Ms[256 + dgrp * 8 + j], M1[j]);
    }
  }
  __syncthreads();
  atomicAdd(&Mbuf[tid], Ms[tid]);
  atomicAdd(&Mbuf[256 + tid], Ms[tid + 256]);
  __threadfence();
  if (tid == 0) lastrank = atomicAdd(cnt, 1u);
  __syncthreads();
  if (lastrank == (unsigned int)(nblocks - 1)){
    float m0v = __hip_atomic_load(&Mbuf[tid], __ATOMIC_RELAXED, __HIP_MEMORY_SCOPE_AGENT);
    float m1v = __hip_atomic_load(&Mbuf[256 + tid], __ATOMIC_RELAXED, __HIP_MEMORY_SCOPE_AGENT);
    a0s[tid] = m0v * Wc[tid];
    a1s[tid] = m1v * Wc[256 + tid];
    __syncthreads();
    for (int off = 128; off > 0; off >>= 1){
      if (tid < off){ a0s[tid] += a0s[tid + off]; a1s[tid] += a1s[tid + off]; }
      __syncthreads();
    }
    if (tid == 0){
      float l0 = a0s[0] + bc[0];
      float l1 = a1s[0] + bc[1];
      out[0] = l0; out[1] = l1;
      float mx = fmaxf(l0, l1);
      float e0 = expf(l0 - mx), e1 = expf(l1 - mx);
      float inv = 1.f / (e0 + e1);
      out[2] = e0 * inv; out[3] = e1 * inv;
    }
  }
}

extern "C" void kernel_launch(void* const* d_in, const int* in_sizes, int n_in,
                              void* d_out, int out_size, void* d_ws, size_t ws_size,
                              hipStream_t stream) {
  const float* x   = (const float*)d_in[0];
  const int*   ei  = (const int*)d_in[1];
  const int*   lab = (const int*)d_in[2];
  const float* Wq  = (const float*)d_in[3];
  const float* bq  = (const float*)d_in[4];
  const float* Wk  = (const float*)d_in[5];
  const float* bk  = (const float*)d_in[6];
  const float* Wv  = (const float*)d_in[7];
  const float* bv  = (const float*)d_in[8];
  const float* Ws  = (const float*)d_in[9];
  const float* bs  = (const float*)d_in[10];
  const float* Wa1 = (const float*)d_in[11];
  const float* ba1 = (const float*)d_in[12];
  const float* Wa2 = (const float*)d_in[13];
  const float* ba2 = (const float*)d_in[14];
  const float* Wc  = (const float*)d_in[15];
  const float* bc  = (const float*)d_in[16];
  float* out = (float*)d_out;

  const int n  = in_sizes[0] / 512;   // 20000
  const int ne = in_sizes[1] / 2;     // 320000

  char* ws = (char*)d_ws;
  size_t off = 0;
  auto take = [&](size_t bytes){ size_t r = off; off += (bytes + 255) & ~(size_t)255; return r; };
  unsigned short* wcatT  = (unsigned short*)(ws + take((size_t)1024 * 512 * 2));
  float*          bcat   = (float*)(ws + take(1024 * 4));
  unsigned short* xbf    = (unsigned short*)(ws + take((size_t)n * 512 * 2));
  unsigned short* qbf    = (unsigned short*)(ws + take((size_t)n * 256 * 2));
  unsigned short* sbf    = (unsigned short*)(ws + take((size_t)n * 256 * 2));
  unsigned char*  kv8    = (unsigned char*)(ws + take((size_t)n * 512));
  unsigned short* hbf    = (unsigned short*)(ws + take((size_t)n * 256 * 2));
  unsigned short* wa1T   = (unsigned short*)(ws + take((size_t)256 * 256 * 2));
  float*          es2    = (float*)(ws + take((size_t)n * 2 * 4));
  size_t zoff = off;
  int*            deg    = (int*)(ws + take((size_t)n * 4));
  int*            cursor = (int*)(ws + take((size_t)n * 4));
  float*          Mbuf   = (float*)(ws + take(512 * 4));
  float*          den_g  = (float*)(ws + take(2 * 4));
  unsigned int*   cnt    = (unsigned int*)(ws + take(4));
  unsigned int*   pcnt   = (unsigned int*)(ws + take(4));
  size_t zlen = off - zoff;
  int*            rowst  = (int*)(ws + take((size_t)(n + 1) * 4));
  int*            csrsrc = (int*)(ws + take((size_t)ne * 4));

  const int z16 = (int)(zlen / 16);
  zero_buf<<<(z16 + 255) / 256, 256, 0, stream>>>((uint4*)(ws + zoff), z16);

  const int nbcv = (n * 64 + 255) / 256;
  const int nbdh = (ne + 255) / 256;
  prep<<<2304 + nbcv + nbdh, 256, 0, stream>>>(x, Wq, Wk, Wv, Ws, bq, bk, bv, bs, Wa1, ei,
                                               xbf, wcatT, bcat, wa1T, deg, rowst, pcnt, n, ne, nbcv);
  const int mblocks = (n + 127) / 128;
  const int nscb = (ne + 255) / 256;
  gemm_qkvs<<<nscb + 8 * mblocks, 256, 0, stream>>>(xbf, wcatT, bcat, qbf, sbf, kv8,
                                                    ei, rowst, cursor, csrsrc, n, ne, mblocks, nscb);
  edge_attn<<<(n + 7) / 8, 256, 0, stream>>>(qbf, sbf, kv8, rowst, csrsrc, hbf, n);
  mlp_mfma<<<(n + 63) / 64, 256, 0, stream>>>(hbf, wa1T, ba1, Wa2, ba2, es2, den_g, n);
  const int nbam = (n + 255) / 256;
  attn_M<<<nbam, 256, 0, stream>>>(es2, den_g, hbf, lab, Mbuf, out + 4, Wc, bc, out, cnt, n, nbam);
  (void)ws_size; (void)out_size; (void)n_in;
}

// Round 17
// 185.062 us; speedup vs baseline: 4.7161x; 4.7161x over previous
//
#include <hip/hip_runtime.h>
#include <hip/hip_bf16.h>
#include <math.h>

typedef float f32x4_t __attribute__((ext_vector_type(4)));
typedef float f32x2_t __attribute__((ext_vector_type(2)));
typedef __bf16 bf16x8_t __attribute__((ext_vector_type(8)));

__device__ __forceinline__ float bf2f(unsigned int u){
  union { float f; unsigned int i; } x; x.i = u << 16; return x.f;
}
__device__ __forceinline__ unsigned short f2bf(float f){
  unsigned int x = __float_as_uint(f);
  unsigned int r = (x + 0x7fffu + ((x >> 16) & 1u)) >> 16;
  return (unsigned short)r;
}
__device__ __forceinline__ unsigned int pk2bf(float a, float b){
  return (unsigned int)f2bf(a) | ((unsigned int)f2bf(b) << 16);
}
// LDS unit swizzle: r = row (0..127), 2-bit XOR applied to 16B-unit index
__device__ __forceinline__ int swz4(int r){ return (r ^ (r >> 2) ^ (r >> 4)) & 3; }

// unpack 8 bf16 (uint4) -> 8 floats, scaled
__device__ __forceinline__ void unp8s(uint4 w, float* f, float s){
  f[0] = bf2f(w.x & 0xffffu) * s; f[1] = bf2f(w.x >> 16) * s;
  f[2] = bf2f(w.y & 0xffffu) * s; f[3] = bf2f(w.y >> 16) * s;
  f[4] = bf2f(w.z & 0xffffu) * s; f[5] = bf2f(w.z >> 16) * s;
  f[6] = bf2f(w.w & 0xffffu) * s; f[7] = bf2f(w.w >> 16) * s;
}
// unpack 4 fp8 e4m3 (one u32) -> 4 floats (HW cvt)
__device__ __forceinline__ void unpf8(unsigned int w, float* f){
  f32x2_t lo = __builtin_amdgcn_cvt_pk_f32_fp8(w, false);
  f32x2_t hi = __builtin_amdgcn_cvt_pk_f32_fp8(w, true);
  f[0] = lo[0]; f[1] = lo[1]; f[2] = hi[0]; f[3] = hi[1];
}
// exact tanh via exp2 (cheap): 1 - 2/(exp2(2*log2e*y)+1)
__device__ __forceinline__ float fast_tanh(float y){
  float e = exp2f(y * 2.8853901817f);
  return 1.0f - 2.0f / (e + 1.0f);
}
// tanh-form gelu (approx to exact-erf gelu, |err| ~1e-3), NaN-free
__device__ __forceinline__ float fast_gelu(float x){
  float x2 = x * x;
  float u = x * fmaf(0.1029527f, x2, 2.3022339f);   // 2*log2e*0.79788456*(1+0.044715*x^2)
  float e = exp2f(u);
  return x - x / (e + 1.0f);
}

#define GLOAD16(gsrc, ldst) \
  __builtin_amdgcn_global_load_lds((const __attribute__((address_space(1))) unsigned int*)(gsrc), \
                                   (__attribute__((address_space(3))) unsigned int*)(ldst), 16, 0, 0)

// ---------------- K-1: zero scratch
__global__ void zero_buf(uint4* __restrict__ p, int n16){
  int i = blockIdx.x * 256 + threadIdx.x;
  if (i < n16) p[i] = make_uint4(0, 0, 0, 0);
}

// ---------------- K0: fused prep — pack_weights(swizzled) | pack_wa1 | convert_x(swizzled) | degree_hist
__global__ void prep(const float* __restrict__ x,
                     const float* __restrict__ Wq, const float* __restrict__ Wk,
                     const float* __restrict__ Wv, const float* __restrict__ Ws,
                     const float* __restrict__ bq, const float* __restrict__ bk,
                     const float* __restrict__ bv, const float* __restrict__ bs,
                     const float* __restrict__ Wa1, const int* __restrict__ ei,
                     unsigned short* __restrict__ xbf, unsigned short* __restrict__ wcatT,
                     float* __restrict__ bcat, unsigned short* __restrict__ wa1T,
                     int* __restrict__ deg, int n, int ne, int nbcv){
  const int b = blockIdx.x, tid = threadIdx.x;
  if (b < 2048){
    int idx = b * 256 + tid;
    int c = idx >> 9, k = idx & 511;
    int sel = c >> 8, cc = c & 255;
    const float* W = (sel == 0) ? Wq : (sel == 1) ? Wk : (sel == 2) ? Wv : Ws;
    int p = ((k >> 3) & 3) ^ swz4(c & 127);
    int dst = c * 512 + (k & ~31) + p * 8 + (k & 7);
    wcatT[dst] = f2bf(W[k * 256 + cc]);
    if (idx < 1024){
      int sel2 = idx >> 8, cc2 = idx & 255;
      const float* B = (sel2 == 0) ? bq : (sel2 == 1) ? bk : (sel2 == 2) ? bv : bs;
      bcat[idx] = B[cc2];
    }
  } else if (b < 2304){
    int idx = (b - 2048) * 256 + tid;
    int c = idx >> 8, k = idx & 255;
    wa1T[idx] = f2bf(Wa1[k * 256 + c]);
  } else if (b < 2304 + nbcv){
    int idx = (b - 2304) * 256 + tid;
    if (idx < n * 64){
      int node = idx >> 6, un = idx & 63;
      int k0 = (un >> 2) * 32, u = un & 3;
      const float* src = x + (size_t)node * 512 + k0 + u * 8;
      float4 f0 = *reinterpret_cast<const float4*>(src);
      float4 f1 = *reinterpret_cast<const float4*>(src + 4);
      uint4 o;
      o.x = pk2bf(f0.x, f0.y); o.y = pk2bf(f0.z, f0.w);
      o.z = pk2bf(f1.x, f1.y); o.w = pk2bf(f1.z, f1.w);
      int p = u ^ swz4(node & 127);
      *reinterpret_cast<uint4*>(xbf + (size_t)node * 512 + k0 + p * 8) = o;
    }
  } else {
    int i = (b - 2304 - nbcv) * 256 + tid;
    if (i < ne) atomicAdd(&deg[ei[ne + i]], 1);
  }
}

// ---------------- K5: exclusive scan, single block, 2-pass blocked
__global__ void scan_deg(const int* __restrict__ deg, int* __restrict__ rowstart, int n, int ne){
  __shared__ int sm[1024];
  int tid = threadIdx.x;
  int per = (n + 1023) / 1024;
  int start = tid * per;
  int sum = 0;
  for (int i = 0; i < per; i++){
    int idx = start + i;
    sum += (idx < n) ? deg[idx] : 0;
  }
  sm[tid] = sum; __syncthreads();
  for (int off = 1; off < 1024; off <<= 1){
    int t = (tid >= off) ? sm[tid - off] : 0;
    __syncthreads();
    sm[tid] += t;
    __syncthreads();
  }
  int run = sm[tid] - sum;
  for (int i = 0; i < per; i++){
    int idx = start + i;
    if (idx < n){
      rowstart[idx] = run;
      run += deg[idx];
    }
  }
  if (tid == 0) rowstart[n] = ne;
}

// ---------------- K3: QKVS GEMM + concurrent edge scatter.
// First nscb blocks scatter edges into CSR (independent, latency-bound — hides under MFMA).
// Remaining blocks: triple-buffered gload_lds GEMM (round-8 proven core), vmcnt(8),
// XCD swizzle, swapped-operand MFMA, bank-uniform LDS-staged epilogue.
__global__ __launch_bounds__(256) void gemm_qkvs(const unsigned short* __restrict__ xbf,
                                                 const unsigned short* __restrict__ wcatT,
                                                 const float* __restrict__ bcat,
                                                 unsigned short* __restrict__ qbf,
                                                 unsigned short* __restrict__ sbf,
                                                 unsigned char* __restrict__ kv8,
                                                 const int* __restrict__ ei,
                                                 const int* __restrict__ rowst,
                                                 int* __restrict__ cursor,
                                                 int* __restrict__ csrsrc,
                                                 int n_nodes, int ne, int mblocks, int nscb){
  __shared__ __align__(16) unsigned char smem[49152];
  const int tid = threadIdx.x;
  if (blockIdx.x < (unsigned)nscb){
    int i = blockIdx.x * 256 + tid;
    if (i < ne){
      int d = ei[ne + i];
      int pos = atomicAdd(&cursor[d], 1);
      csrsrc[rowst[d] + pos] = ei[i] << 9;
    }
    return;
  }
  const int bid = blockIdx.x - nscb;
  const int lane = tid & 63, wave = tid >> 6;
  const int wm = wave >> 1, wn = wave & 1;
  const int g = (bid & 7) * mblocks + (bid >> 3);
  const int m_blk = g >> 3, n_blk = g & 7;
  const int m0 = m_blk * 128, n0 = n_blk * 128;
  const int lrow = lane >> 2;
  const int lcol = (lane & 3) * 8;
  const int rA0 = min(m0 + wave * 16 + lrow, n_nodes - 1);
  const int rA1 = min(m0 + (wave + 4) * 16 + lrow, n_nodes - 1);
  const int rB0 = n0 + wave * 16 + lrow;
  const int rB1 = rB0 + 64;
  const int r = lane & 15, q4 = lane >> 4;
  const unsigned short* aG0 = xbf   + (size_t)rA0 * 512 + lcol;
  const unsigned short* aG1 = xbf   + (size_t)rA1 * 512 + lcol;
  const unsigned short* bG0 = wcatT + (size_t)rB0 * 512 + lcol;
  const unsigned short* bG1 = wcatT + (size_t)rB1 * 512 + lcol;
  int aoff[4], boff[4];
  #pragma unroll
  for (int mi = 0; mi < 4; mi++){ int rr = wm * 64 + mi * 16 + r; aoff[mi] = rr * 32 + ((q4 ^ swz4(rr)) * 8); }
  #pragma unroll
  for (int ni = 0; ni < 4; ni++){ int rb = wn * 64 + ni * 16 + r; boff[ni] = rb * 32 + ((q4 ^ swz4(rb)) * 8); }
  f32x4_t acc[4][4] = {};
#define STAGE(base, k0) { \
    unsigned short* As_ = (unsigned short*)(smem + (base)); \
    unsigned short* Bs_ = (unsigned short*)(smem + (base) + 8192); \
    GLOAD16(aG0 + (k0), &As_[wave * 512]); \
    GLOAD16(aG1 + (k0), &As_[(wave + 4) * 512]); \
    GLOAD16(bG0 + (k0), &Bs_[wave * 512]); \
    GLOAD16(bG1 + (k0), &Bs_[(wave + 4) * 512]); \
  }
  STAGE(0, 0);
  STAGE(16384, 32);
  int cbase = 0;
  int sbase = 32768;
  for (int t = 0; t < 16; t++){
    if (t + 2 < 16){
      STAGE(sbase, (t + 2) * 32);
      asm volatile("s_waitcnt vmcnt(8)" ::: "memory");
    } else if (t + 1 < 16){
      asm volatile("s_waitcnt vmcnt(4)" ::: "memory");
    } else {
      asm volatile("s_waitcnt vmcnt(0)" ::: "memory");
    }
    __builtin_amdgcn_s_barrier();
    asm volatile("" ::: "memory");
    const unsigned short* As = (const unsigned short*)(smem + cbase);
    const unsigned short* Bs = (const unsigned short*)(smem + cbase + 8192);
    bf16x8_t a[4], b[4];
    #pragma unroll
    for (int mi = 0; mi < 4; mi++) a[mi] = *reinterpret_cast<const bf16x8_t*>(&As[aoff[mi]]);
    #pragma unroll
    for (int ni = 0; ni < 4; ni++) b[ni] = *reinterpret_cast<const bf16x8_t*>(&Bs[boff[ni]]);
    #pragma unroll
    for (int mi = 0; mi < 4; mi++)
      #pragma unroll
      for (int ni = 0; ni < 4; ni++)
        acc[mi][ni] = __builtin_amdgcn_mfma_f32_16x16x32_bf16(b[ni], a[mi], acc[mi][ni], 0, 0, 0);
    __builtin_amdgcn_s_barrier();
    asm volatile("" ::: "memory");
    cbase += 16384; if (cbase == 49152) cbase = 0;
    sbase += 16384; if (sbase == 49152) sbase = 0;
  }
#undef STAGE
  const bool isQ = (n_blk < 2), isS = (n_blk >= 6);
  if (isQ || isS){
    unsigned short* St = (unsigned short*)smem;   // [64][152] bf16
    unsigned short* outp = isQ ? qbf : sbf;
    const int colhalf = isQ ? n_blk : (n_blk - 6);
    #pragma unroll
    for (int ch = 0; ch < 2; ch++){
      if (wm == ch){
        #pragma unroll
        for (int mi = 0; mi < 4; mi++){
          #pragma unroll
          for (int ni = 0; ni < 4; ni++){
            int mloc = mi * 16 + r;
            int nl = wn * 64 + ni * 16 + q4 * 4;
            float4 bb = *reinterpret_cast<const float4*>(&bcat[n0 + nl]);
            uint2 w;
            w.x = pk2bf(acc[mi][ni][0] + bb.x, acc[mi][ni][1] + bb.y);
            w.y = pk2bf(acc[mi][ni][2] + bb.z, acc[mi][ni][3] + bb.w);
            *reinterpret_cast<uint2*>(&St[mloc * 152 + nl]) = w;
          }
        }
      }
      __syncthreads();
      #pragma unroll
      for (int it = 0; it < 4; it++){
        int u = it * 256 + tid;
        int row = u >> 4, seg = (u & 15) * 8;
        int node = m0 + ch * 64 + row;
        if (node < n_nodes){
          uint4 v = *reinterpret_cast<const uint4*>(&St[row * 152 + seg]);
          *reinterpret_cast<uint4*>(outp + (size_t)node * 256 + colhalf * 128 + seg) = v;
        }
      }
      __syncthreads();
    }
  } else {
    unsigned char* St8 = smem;                    // [64][144] fp8
    #pragma unroll
    for (int ch = 0; ch < 2; ch++){
      if (wm == ch){
        #pragma unroll
        for (int mi = 0; mi < 4; mi++){
          #pragma unroll
          for (int ni = 0; ni < 4; ni++){
            int mloc = mi * 16 + r;
            int nl = wn * 64 + ni * 16 + q4 * 4;
            float4 bb = *reinterpret_cast<const float4*>(&bcat[n0 + nl]);
            int u = 0;
            u = __builtin_amdgcn_cvt_pk_fp8_f32(acc[mi][ni][0] + bb.x, acc[mi][ni][1] + bb.y, u, false);
            u = __builtin_amdgcn_cvt_pk_fp8_f32(acc[mi][ni][2] + bb.z, acc[mi][ni][3] + bb.w, u, true);
            *reinterpret_cast<unsigned int*>(&St8[mloc * 144 + nl]) = (unsigned int)u;
          }
        }
      }
      __syncthreads();
      #pragma unroll
      for (int it = 0; it < 2; it++){
        int u = it * 256 + tid;
        int row = u >> 3, seg = (u & 7) * 16;
        int node = m0 + ch * 64 + row;
        if (node < n_nodes){
          uint4 v = *reinterpret_cast<const uint4*>(&St8[row * 144 + seg]);
          *reinterpret_cast<uint4*>(kv8 + (size_t)node * 512 + (n_blk - 2) * 128 + seg) = v;
        }
      }
      __syncthreads();
    }
  }
}

// ---------------- K7: per-dst online-softmax aggregation
// fp8 K/V (combined 512B row), 16 lanes/edge, 2 chains/node, 2 nodes/wave,
// pair-processing + pair prefetch per chain, shfl_xor(16) merge, fast gelu.
__global__ __launch_bounds__(256) void edge_attn(const unsigned short* __restrict__ qbf,
                                                 const unsigned short* __restrict__ sbf,
                                                 const unsigned char* __restrict__ kv8,
                                                 const int* __restrict__ rowstart,
                                                 const int* __restrict__ csrsrc,
                                                 unsigned short* __restrict__ hbf, int n_nodes){
  const int tid = threadIdx.x;
  const int lane = tid & 63, wave = tid >> 6;
  const int g = lane >> 4, t = lane & 15;
  const int chain = g & 1;
  const int node = blockIdx.x * 8 + wave * 2 + (g >> 1);
  const bool active = node < n_nodes;
  const int nd = active ? node : 0;
  const float qs = 0.0625f * 1.44269504088896340736f;  // (1/sqrt(256)) * log2(e)
  float q[16];
  {
    const unsigned short* qp = qbf + (size_t)nd * 256 + t * 16;
    uint4 w0 = *reinterpret_cast<const uint4*>(qp);
    uint4 w1 = *reinterpret_cast<const uint4*>(qp + 8);
    unp8s(w0, q, qs); unp8s(w1, q + 8, qs);
  }
  int rs = rowstart[nd];
  int re = active ? rowstart[nd + 1] : rs;
  float m = -1e30f, den = 0.f;
  float acc[16];
  #pragma unroll
  for (int j = 0; j < 16; j++) acc[j] = 0.f;
  const int i0 = rs + chain;
  uint4 kA = make_uint4(0,0,0,0), vA = kA, kB = kA, vB = kA;
  if (i0 < re){
    const unsigned char* p1 = kv8 + (size_t)csrsrc[i0] + t * 16;
    kA = *reinterpret_cast<const uint4*>(p1);
    vA = *reinterpret_cast<const uint4*>(p1 + 256);
    if (i0 + 2 < re){
      const unsigned char* p2 = kv8 + (size_t)csrsrc[i0 + 2] + t * 16;
      kB = *reinterpret_cast<const uint4*>(p2);
      vB = *reinterpret_cast<const uint4*>(p2 + 256);
    }
  }
  for (int i = i0; i < re; i += 4){
    uint4 k1 = kA, v1 = vA, k2 = kB, v2 = vB;
    const bool has2 = (i + 2 < re);
    if (i + 4 < re){
      const unsigned char* p1 = kv8 + (size_t)csrsrc[i + 4] + t * 16;
      kA = *reinterpret_cast<const uint4*>(p1);
      vA = *reinterpret_cast<const uint4*>(p1 + 256);
      if (i + 6 < re){
        const unsigned char* p2 = kv8 + (size_t)csrsrc[i + 6] + t * 16;
        kB = *reinterpret_cast<const uint4*>(p2);
        vB = *reinterpret_cast<const uint4*>(p2 + 256);
      }
    }
    float kf1[16], kf2[16];
    unpf8(k1.x, kf1); unpf8(k1.y, kf1 + 4); unpf8(k1.z, kf1 + 8); unpf8(k1.w, kf1 + 12);
    unpf8(k2.x, kf2); unpf8(k2.y, kf2 + 4); unpf8(k2.z, kf2 + 8); unpf8(k2.w, kf2 + 12);
    float s1 = 0.f, s2 = 0.f;
    #pragma unroll
    for (int j = 0; j < 16; j++){ s1 = fmaf(q[j], kf1[j], s1); s2 = fmaf(q[j], kf2[j], s2); }
    s1 += __shfl_xor(s1, 1); s2 += __shfl_xor(s2, 1);
    s1 += __shfl_xor(s1, 2); s2 += __shfl_xor(s2, 2);
    s1 += __shfl_xor(s1, 4); s2 += __shfl_xor(s2, 4);
    s1 += __shfl_xor(s1, 8); s2 += __shfl_xor(s2, 8);
    if (!has2) s2 = -1e30f;
    float vf1[16], vf2[16];
    unpf8(v1.x, vf1); unpf8(v1.y, vf1 + 4); unpf8(v1.z, vf1 + 8); unpf8(v1.w, vf1 + 12);
    unpf8(v2.x, vf2); unpf8(v2.y, vf2 + 4); unpf8(v2.z, vf2 + 8); unpf8(v2.w, vf2 + 12);
    float mn = fmaxf(m, fmaxf(s1, s2));
    float sc = exp2f(m - mn);
    float e1 = exp2f(s1 - mn);
    float e2 = exp2f(s2 - mn);
    den = den * sc + e1 + e2;
    #pragma unroll
    for (int j = 0; j < 16; j++)
      acc[j] = fmaf(acc[j], sc, fmaf(e1, vf1[j], e2 * vf2[j]));
    m = mn;
  }
  // merge the two chains (lane ^ 16 pairs groups 0<->1, 2<->3)
  {
    float mo  = __shfl_xor(m, 16);
    float dno = __shfl_xor(den, 16);
    float mn  = fmaxf(m, mo);
    float a_  = exp2f(m - mn);
    float b_  = exp2f(mo - mn);
    den = den * a_ + dno * b_;
    #pragma unroll
    for (int j = 0; j < 16; j++){
      float oth = __shfl_xor(acc[j], 16);
      acc[j] = acc[j] * a_ + oth * b_;
    }
  }
  float inv = (den > 0.f) ? 1.f / den : 0.f;
  const unsigned short* sp = sbf + (size_t)nd * 256 + t * 16;
  uint4 s0 = *reinterpret_cast<const uint4*>(sp);
  uint4 s1v = *reinterpret_cast<const uint4*>(sp + 8);
  float sf[16]; unp8s(s0, sf, 1.0f); unp8s(s1v, sf + 8, 1.0f);
  unsigned int o[8];
  #pragma unroll
  for (int j = 0; j < 8; j++){
    float h0 = fast_gelu(acc[2 * j] * inv + sf[2 * j]);
    float h1 = fast_gelu(acc[2 * j + 1] * inv + sf[2 * j + 1]);
    o[j] = (unsigned int)f2bf(h0) | ((unsigned int)f2bf(h1) << 16);
  }
  if (active && chain == 0){
    uint4* dst = reinterpret_cast<uint4*>(hbf + (size_t)node * 256 + t * 16);
    dst[0] = make_uint4(o[0], o[1], o[2], o[3]);
    dst[1] = make_uint4(o[4], o[5], o[6], o[7]);
  }
}

// ---------------- K8: es2[n][2] = exp(tanh(hbf@Wa1 + ba1)@Wa2 + ba2); den_g += block sums
__global__ __launch_bounds__(256) void mlp_mfma(const unsigned short* __restrict__ hbf,
                                                const unsigned short* __restrict__ wa1T,
                                                const float* __restrict__ ba1,
                                                const float* __restrict__ Wa2,
                                                const float* __restrict__ ba2,
                                                float* __restrict__ es2,
                                                float* __restrict__ den_g, int n_nodes){
  __shared__ __align__(16) unsigned short As[64 * 72];
  __shared__ float s2s[64][2];
  const int tid = threadIdx.x;
  const int lane = tid & 63, wave = tid >> 6;
  const int m0 = blockIdx.x * 64;
  const int c0 = wave * 64;
  const int r = lane & 15, rg = (lane >> 4) * 4;
  if (tid < 128) s2s[tid >> 1][tid & 1] = 0.f;
  f32x4_t acc[4][4] = {};
  for (int k0 = 0; k0 < 256; k0 += 64){
    int arow = tid >> 2, akc = (tid & 3) * 16;
    uint4 a0v = make_uint4(0,0,0,0), a1v = make_uint4(0,0,0,0);
    if (m0 + arow < n_nodes){
      const unsigned short* src = hbf + (size_t)(m0 + arow) * 256 + k0 + akc;
      a0v = *reinterpret_cast<const uint4*>(src);
      a1v = *reinterpret_cast<const uint4*>(src + 8);
    }
    *reinterpret_cast<uint4*>(&As[arow * 72 + akc]) = a0v;
    *reinterpret_cast<uint4*>(&As[arow * 72 + akc + 8]) = a1v;
    __syncthreads();
    #pragma unroll
    for (int kk = 0; kk < 2; kk++){
      int kg = kk * 32 + (lane >> 4) * 8;
      bf16x8_t a[4], b[4];
      #pragma unroll
      for (int mi = 0; mi < 4; mi++)
        a[mi] = *reinterpret_cast<const bf16x8_t*>(&As[(mi * 16 + r) * 72 + kg]);
      #pragma unroll
      for (int ni = 0; ni < 4; ni++)
        b[ni] = *reinterpret_cast<const bf16x8_t*>(wa1T + (size_t)(c0 + ni * 16 + r) * 256 + k0 + kg);
      #pragma unroll
      for (int mi = 0; mi < 4; mi++)
        #pragma unroll
        for (int ni = 0; ni < 4; ni++)
          acc[mi][ni] = __builtin_amdgcn_mfma_f32_16x16x32_bf16(a[mi], b[ni], acc[mi][ni], 0, 0, 0);
    }
    __syncthreads();
  }
  float w20[4], w21[4], b1c[4];
  #pragma unroll
  for (int ni = 0; ni < 4; ni++){
    int col = c0 + ni * 16 + r;
    w20[ni] = Wa2[col * 2]; w21[ni] = Wa2[col * 2 + 1]; b1c[ni] = ba1[col];
  }
  #pragma unroll
  for (int mi = 0; mi < 4; mi++){
    #pragma unroll
    for (int j = 0; j < 4; j++){
      float t0 = 0.f, t1 = 0.f;
      #pragma unroll
      for (int ni = 0; ni < 4; ni++){
        float t = fast_tanh(acc[mi][ni][j] + b1c[ni]);
        t0 += t * w20[ni]; t1 += t * w21[ni];
      }
      t0 += __shfl_xor(t0, 1); t0 += __shfl_xor(t0, 2);
      t0 += __shfl_xor(t0, 4); t0 += __shfl_xor(t0, 8);
      t1 += __shfl_xor(t1, 1); t1 += __shfl_xor(t1, 2);
      t1 += __shfl_xor(t1, 4); t1 += __shfl_xor(t1, 8);
      if (r == 0){
        int row = mi * 16 + rg + j;
        atomicAdd(&s2s[row][0], t0);
        atomicAdd(&s2s[row][1], t1);
      }
    }
  }
  __syncthreads();
  if (tid < 128){
    int row = tid >> 1, c = tid & 1;
    int node = m0 + row;
    float e = 0.f;
    if (node < n_nodes){
      e = expf(s2s[row][c] + ba2[c]);
      es2[node * 2 + c] = e;
    }
    float sum = e;
    sum += __shfl_xor(sum, 2);  sum += __shfl_xor(sum, 4);
    sum += __shfl_xor(sum, 8);  sum += __shfl_xor(sum, 16);
    sum += __shfl_xor(sum, 32);
    if ((tid & 63) < 2) atomicAdd(&den_g[c], sum);
  }
}

// ---------------- K10: attn + A output + M accumulation + fused logits (completion counter)
__global__ __launch_bounds__(256) void attn_M(const float* __restrict__ es2, const float* __restrict__ den_g,
                                              const unsigned short* __restrict__ hbf, const int* __restrict__ label,
                                              float* __restrict__ Mbuf, float* __restrict__ outA,
                                              const float* __restrict__ Wc, const float* __restrict__ bc,
                                              float* __restrict__ out, unsigned int* __restrict__ cnt,
                                              int n, int nblocks){
  __shared__ float a0s[256], a1s[256];
  __shared__ float Ms[512];
  __shared__ unsigned int lastrank;
  int tid = threadIdx.x;
  int n0 = blockIdx.x * 256;
  int node = n0 + tid;
  float i0 = 1.f / den_g[0], i1 = 1.f / den_g[1];
  float a0 = 0.f, a1 = 0.f;
  if (node < n){
    a0 = es2[2 * node] * i0;
    a1 = es2[2 * node + 1] * i1;
    outA[node] = (label[0] == 0) ? a0 : a1;
  }
  a0s[tid] = a0; a1s[tid] = a1;
  Ms[tid] = 0.f; Ms[tid + 256] = 0.f;
  __syncthreads();
  const int dgrp = tid & 31;
  const int nl = tid >> 5;
  float M0[8] = {}, M1[8] = {};
  for (int i = nl; i < 256; i += 8){
    int nd = n0 + i;
    if (nd >= n) break;
    uint4 w = *reinterpret_cast<const uint4*>(hbf + (size_t)nd * 256 + dgrp * 8);
    float f[8]; unp8s(w, f, 1.0f);
    float A0 = a0s[i], A1 = a1s[i];
    #pragma unroll
    for (int j = 0; j < 8; j++){
      M0[j] = fmaf(A0, f[j], M0[j]);
      M1[j] = fmaf(A1, f[j], M1[j]);
    }
  }
  #pragma unroll
  for (int j = 0; j < 8; j++){
    M0[j] += __shfl_xor(M0[j], 32);
    M1[j] += __shfl_xor(M1[j], 32);
  }
  if ((tid & 32) == 0){
    #pragma unroll
    for (int j = 0; j < 8; j++){
      atomicAdd(&Ms[dgrp * 8 + j], M0[j]);
      atomicAdd(&Ms[256 + dgrp * 8 + j], M1[j]);
    }
  }
  __syncthreads();
  atomicAdd(&Mbuf[tid], Ms[tid]);
  atomicAdd(&Mbuf[256 + tid], Ms[tid + 256]);
  __threadfence();
  if (tid == 0) lastrank = atomicAdd(cnt, 1u);
  __syncthreads();
  if (lastrank == (unsigned int)(nblocks - 1)){
    float m0v = __hip_atomic_load(&Mbuf[tid], __ATOMIC_RELAXED, __HIP_MEMORY_SCOPE_AGENT);
    float m1v = __hip_atomic_load(&Mbuf[256 + tid], __ATOMIC_RELAXED, __HIP_MEMORY_SCOPE_AGENT);
    a0s[tid] = m0v * Wc[tid];
    a1s[tid] = m1v * Wc[256 + tid];
    __syncthreads();
    for (int off = 128; off > 0; off >>= 1){
      if (tid < off){ a0s[tid] += a0s[tid + off]; a1s[tid] += a1s[tid + off]; }
      __syncthreads();
    }
    if (tid == 0){
      float l0 = a0s[0] + bc[0];
      float l1 = a1s[0] + bc[1];
      out[0] = l0; out[1] = l1;
      float mx = fmaxf(l0, l1);
      float e0 = expf(l0 - mx), e1 = expf(l1 - mx);
      float inv = 1.f / (e0 + e1);
      out[2] = e0 * inv; out[3] = e1 * inv;
    }
  }
}

extern "C" void kernel_launch(void* const* d_in, const int* in_sizes, int n_in,
                              void* d_out, int out_size, void* d_ws, size_t ws_size,
                              hipStream_t stream) {
  const float* x   = (const float*)d_in[0];
  const int*   ei  = (const int*)d_in[1];
  const int*   lab = (const int*)d_in[2];
  const float* Wq  = (const float*)d_in[3];
  const float* bq  = (const float*)d_in[4];
  const float* Wk  = (const float*)d_in[5];
  const float* bk  = (const float*)d_in[6];
  const float* Wv  = (const float*)d_in[7];
  const float* bv  = (const float*)d_in[8];
  const float* Ws  = (const float*)d_in[9];
  const float* bs  = (const float*)d_in[10];
  const float* Wa1 = (const float*)d_in[11];
  const float* ba1 = (const float*)d_in[12];
  const float* Wa2 = (const float*)d_in[13];
  const float* ba2 = (const float*)d_in[14];
  const float* Wc  = (const float*)d_in[15];
  const float* bc  = (const float*)d_in[16];
  float* out = (float*)d_out;

  const int n  = in_sizes[0] / 512;   // 20000
  const int ne = in_sizes[1] / 2;     // 320000

  char* ws = (char*)d_ws;
  size_t off = 0;
  auto take = [&](size_t bytes){ size_t r = off; off += (bytes + 255) & ~(size_t)255; return r; };
  unsigned short* wcatT  = (unsigned short*)(ws + take((size_t)1024 * 512 * 2));
  float*          bcat   = (float*)(ws + take(1024 * 4));
  unsigned short* xbf    = (unsigned short*)(ws + take((size_t)n * 512 * 2));
  unsigned short* qbf    = (unsigned short*)(ws + take((size_t)n * 256 * 2));
  unsigned short* sbf    = (unsigned short*)(ws + take((size_t)n * 256 * 2));
  unsigned char*  kv8    = (unsigned char*)(ws + take((size_t)n * 512));
  unsigned short* hbf    = (unsigned short*)(ws + take((size_t)n * 256 * 2));
  unsigned short* wa1T   = (unsigned short*)(ws + take((size_t)256 * 256 * 2));
  float*          es2    = (float*)(ws + take((size_t)n * 2 * 4));
  size_t zoff = off;
  int*            deg    = (int*)(ws + take((size_t)n * 4));
  int*            cursor = (int*)(ws + take((size_t)n * 4));
  float*          Mbuf   = (float*)(ws + take(512 * 4));
  float*          den_g  = (float*)(ws + take(2 * 4));
  unsigned int*   cnt    = (unsigned int*)(ws + take(4));
  size_t zlen = off - zoff;
  int*            rowst  = (int*)(ws + take((size_t)(n + 1) * 4));
  int*            csrsrc = (int*)(ws + take((size_t)ne * 4));

  const int z16 = (int)(zlen / 16);
  zero_buf<<<(z16 + 255) / 256, 256, 0, stream>>>((uint4*)(ws + zoff), z16);

  const int nbcv = (n * 64 + 255) / 256;
  const int nbdh = (ne + 255) / 256;
  prep<<<2304 + nbcv + nbdh, 256, 0, stream>>>(x, Wq, Wk, Wv, Ws, bq, bk, bv, bs, Wa1, ei,
                                               xbf, wcatT, bcat, wa1T, deg, n, ne, nbcv);
  scan_deg<<<1, 1024, 0, stream>>>(deg, rowst, n, ne);
  const int mblocks = (n + 127) / 128;
  const int nscb = (ne + 255) / 256;
  gemm_qkvs<<<nscb + 8 * mblocks, 256, 0, stream>>>(xbf, wcatT, bcat, qbf, sbf, kv8,
                                                    ei, rowst, cursor, csrsrc, n, ne, mblocks, nscb);
  edge_attn<<<(n + 7) / 8, 256, 0, stream>>>(qbf, sbf, kv8, rowst, csrsrc, hbf, n);
  mlp_mfma<<<(n + 63) / 64, 256, 0, stream>>>(hbf, wa1T, ba1, Wa2, ba2, es2, den_g, n);
  const int nbam = (n + 255) / 256;
  attn_M<<<nbam, 256, 0, stream>>>(es2, den_g, hbf, lab, Mbuf, out + 4, Wc, bc, out, cnt, n, nbam);
  (void)ws_size; (void)out_size; (void)n_in;
}

// Round 18
// 181.262 us; speedup vs baseline: 4.8150x; 1.0210x over previous
//
#include <hip/hip_runtime.h>
#include <hip/hip_bf16.h>
#include <math.h>

typedef float f32x4_t __attribute__((ext_vector_type(4)));
typedef float f32x2_t __attribute__((ext_vector_type(2)));
typedef __bf16 bf16x8_t __attribute__((ext_vector_type(8)));

__device__ __forceinline__ float bf2f(unsigned int u){
  union { float f; unsigned int i; } x; x.i = u << 16; return x.f;
}
__device__ __forceinline__ unsigned short f2bf(float f){
  unsigned int x = __float_as_uint(f);
  unsigned int r = (x + 0x7fffu + ((x >> 16) & 1u)) >> 16;
  return (unsigned short)r;
}
__device__ __forceinline__ unsigned int pk2bf(float a, float b){
  return (unsigned int)f2bf(a) | ((unsigned int)f2bf(b) << 16);
}
// LDS unit swizzle: r = row (0..127), 2-bit XOR applied to 16B-unit index
__device__ __forceinline__ int swz4(int r){ return (r ^ (r >> 2) ^ (r >> 4)) & 3; }

// unpack 8 bf16 (uint4) -> 8 floats, scaled
__device__ __forceinline__ void unp8s(uint4 w, float* f, float s){
  f[0] = bf2f(w.x & 0xffffu) * s; f[1] = bf2f(w.x >> 16) * s;
  f[2] = bf2f(w.y & 0xffffu) * s; f[3] = bf2f(w.y >> 16) * s;
  f[4] = bf2f(w.z & 0xffffu) * s; f[5] = bf2f(w.z >> 16) * s;
  f[6] = bf2f(w.w & 0xffffu) * s; f[7] = bf2f(w.w >> 16) * s;
}
// unpack 4 fp8 e4m3 (one u32) -> 4 floats (HW cvt)
__device__ __forceinline__ void unpf8(unsigned int w, float* f){
  f32x2_t lo = __builtin_amdgcn_cvt_pk_f32_fp8(w, false);
  f32x2_t hi = __builtin_amdgcn_cvt_pk_f32_fp8(w, true);
  f[0] = lo[0]; f[1] = lo[1]; f[2] = hi[0]; f[3] = hi[1];
}
// exact tanh via exp2 (cheap): 1 - 2/(exp2(2*log2e*y)+1)
__device__ __forceinline__ float fast_tanh(float y){
  float e = exp2f(y * 2.8853901817f);
  return 1.0f - 2.0f / (e + 1.0f);
}
// tanh-form gelu (approx to exact-erf gelu, |err| ~1e-3), NaN-free
__device__ __forceinline__ float fast_gelu(float x){
  float x2 = x * x;
  float u = x * fmaf(0.1029527f, x2, 2.3022339f);   // 2*log2e*0.79788456*(1+0.044715*x^2)
  float e = exp2f(u);
  return x - x / (e + 1.0f);
}

#define GLOAD16(gsrc, ldst) \
  __builtin_amdgcn_global_load_lds((const __attribute__((address_space(1))) unsigned int*)(gsrc), \
                                   (__attribute__((address_space(3))) unsigned int*)(ldst), 16, 0, 0)

// ---------------- K-1: zero scratch
__global__ void zero_buf(uint4* __restrict__ p, int n16){
  int i = blockIdx.x * 256 + threadIdx.x;
  if (i < n16) p[i] = make_uint4(0, 0, 0, 0);
}

// ---------------- K0: fused prep — pack_weights(swizzled) | pack_wa1 | convert_x(swizzled) | degree_hist
__global__ void prep(const float* __restrict__ x,
                     const float* __restrict__ Wq, const float* __restrict__ Wk,
                     const float* __restrict__ Wv, const float* __restrict__ Ws,
                     const float* __restrict__ bq, const float* __restrict__ bk,
                     const float* __restrict__ bv, const float* __restrict__ bs,
                     const float* __restrict__ Wa1, const int* __restrict__ ei,
                     unsigned short* __restrict__ xbf, unsigned short* __restrict__ wcatT,
                     float* __restrict__ bcat, unsigned short* __restrict__ wa1T,
                     int* __restrict__ deg, int n, int ne, int nbcv){
  const int b = blockIdx.x, tid = threadIdx.x;
  if (b < 2048){
    int idx = b * 256 + tid;
    int c = idx >> 9, k = idx & 511;
    int sel = c >> 8, cc = c & 255;
    const float* W = (sel == 0) ? Wq : (sel == 1) ? Wk : (sel == 2) ? Wv : Ws;
    int p = ((k >> 3) & 3) ^ swz4(c & 127);
    int dst = c * 512 + (k & ~31) + p * 8 + (k & 7);
    wcatT[dst] = f2bf(W[k * 256 + cc]);
    if (idx < 1024){
      int sel2 = idx >> 8, cc2 = idx & 255;
      const float* B = (sel2 == 0) ? bq : (sel2 == 1) ? bk : (sel2 == 2) ? bv : bs;
      bcat[idx] = B[cc2];
    }
  } else if (b < 2304){
    int idx = (b - 2048) * 256 + tid;
    int c = idx >> 8, k = idx & 255;
    wa1T[idx] = f2bf(Wa1[k * 256 + c]);
  } else if (b < 2304 + nbcv){
    int idx = (b - 2304) * 256 + tid;
    if (idx < n * 64){
      int node = idx >> 6, un = idx & 63;
      int k0 = (un >> 2) * 32, u = un & 3;
      const float* src = x + (size_t)node * 512 + k0 + u * 8;
      float4 f0 = *reinterpret_cast<const float4*>(src);
      float4 f1 = *reinterpret_cast<const float4*>(src + 4);
      uint4 o;
      o.x = pk2bf(f0.x, f0.y); o.y = pk2bf(f0.z, f0.w);
      o.z = pk2bf(f1.x, f1.y); o.w = pk2bf(f1.z, f1.w);
      int p = u ^ swz4(node & 127);
      *reinterpret_cast<uint4*>(xbf + (size_t)node * 512 + k0 + p * 8) = o;
    }
  } else {
    int i = (b - 2304 - nbcv) * 256 + tid;
    if (i < ne) atomicAdd(&deg[ei[ne + i]], 1);
  }
}

// ---------------- K5: exclusive scan, single block, 2-pass blocked
__global__ void scan_deg(const int* __restrict__ deg, int* __restrict__ rowstart, int n, int ne){
  __shared__ int sm[1024];
  int tid = threadIdx.x;
  int per = (n + 1023) / 1024;
  int start = tid * per;
  int sum = 0;
  for (int i = 0; i < per; i++){
    int idx = start + i;
    sum += (idx < n) ? deg[idx] : 0;
  }
  sm[tid] = sum; __syncthreads();
  for (int off = 1; off < 1024; off <<= 1){
    int t = (tid >= off) ? sm[tid - off] : 0;
    __syncthreads();
    sm[tid] += t;
    __syncthreads();
  }
  int run = sm[tid] - sum;
  for (int i = 0; i < per; i++){
    int idx = start + i;
    if (idx < n){
      rowstart[idx] = run;
      run += deg[idx];
    }
  }
  if (tid == 0) rowstart[n] = ne;
}

// ---------------- K3: QKVS GEMM + concurrent edge scatter.
// GEMM blocks come FIRST (start MFMA at t=0); scatter blocks (latency-bound) trail and
// fill the GEMM's drain. Triple-buffered gload_lds (round-8 proven core), vmcnt(8),
// XCD swizzle, swapped-operand MFMA, bank-uniform LDS-staged epilogue.
__global__ __launch_bounds__(256) void gemm_qkvs(const unsigned short* __restrict__ xbf,
                                                 const unsigned short* __restrict__ wcatT,
                                                 const float* __restrict__ bcat,
                                                 unsigned short* __restrict__ qbf,
                                                 unsigned short* __restrict__ sbf,
                                                 unsigned char* __restrict__ kv8,
                                                 const int* __restrict__ ei,
                                                 const int* __restrict__ rowst,
                                                 int* __restrict__ cursor,
                                                 int* __restrict__ csrsrc,
                                                 int n_nodes, int ne, int mblocks, int ngemm){
  __shared__ __align__(16) unsigned char smem[49152];
  const int tid = threadIdx.x;
  if (blockIdx.x >= (unsigned)ngemm){
    int i = (blockIdx.x - ngemm) * 256 + tid;
    if (i < ne){
      int d = ei[ne + i];
      int pos = atomicAdd(&cursor[d], 1);
      csrsrc[rowst[d] + pos] = ei[i] << 9;
    }
    return;
  }
  const int bid = blockIdx.x;
  const int lane = tid & 63, wave = tid >> 6;
  const int wm = wave >> 1, wn = wave & 1;
  const int g = (bid & 7) * mblocks + (bid >> 3);
  const int m_blk = g >> 3, n_blk = g & 7;
  const int m0 = m_blk * 128, n0 = n_blk * 128;
  const int lrow = lane >> 2;
  const int lcol = (lane & 3) * 8;
  const int rA0 = min(m0 + wave * 16 + lrow, n_nodes - 1);
  const int rA1 = min(m0 + (wave + 4) * 16 + lrow, n_nodes - 1);
  const int rB0 = n0 + wave * 16 + lrow;
  const int rB1 = rB0 + 64;
  const int r = lane & 15, q4 = lane >> 4;
  const unsigned short* aG0 = xbf   + (size_t)rA0 * 512 + lcol;
  const unsigned short* aG1 = xbf   + (size_t)rA1 * 512 + lcol;
  const unsigned short* bG0 = wcatT + (size_t)rB0 * 512 + lcol;
  const unsigned short* bG1 = wcatT + (size_t)rB1 * 512 + lcol;
  int aoff[4], boff[4];
  #pragma unroll
  for (int mi = 0; mi < 4; mi++){ int rr = wm * 64 + mi * 16 + r; aoff[mi] = rr * 32 + ((q4 ^ swz4(rr)) * 8); }
  #pragma unroll
  for (int ni = 0; ni < 4; ni++){ int rb = wn * 64 + ni * 16 + r; boff[ni] = rb * 32 + ((q4 ^ swz4(rb)) * 8); }
  f32x4_t acc[4][4] = {};
#define STAGE(base, k0) { \
    unsigned short* As_ = (unsigned short*)(smem + (base)); \
    unsigned short* Bs_ = (unsigned short*)(smem + (base) + 8192); \
    GLOAD16(aG0 + (k0), &As_[wave * 512]); \
    GLOAD16(aG1 + (k0), &As_[(wave + 4) * 512]); \
    GLOAD16(bG0 + (k0), &Bs_[wave * 512]); \
    GLOAD16(bG1 + (k0), &Bs_[(wave + 4) * 512]); \
  }
  STAGE(0, 0);
  STAGE(16384, 32);
  int cbase = 0;
  int sbase = 32768;
  for (int t = 0; t < 16; t++){
    if (t + 2 < 16){
      STAGE(sbase, (t + 2) * 32);
      asm volatile("s_waitcnt vmcnt(8)" ::: "memory");
    } else if (t + 1 < 16){
      asm volatile("s_waitcnt vmcnt(4)" ::: "memory");
    } else {
      asm volatile("s_waitcnt vmcnt(0)" ::: "memory");
    }
    __builtin_amdgcn_s_barrier();
    asm volatile("" ::: "memory");
    const unsigned short* As = (const unsigned short*)(smem + cbase);
    const unsigned short* Bs = (const unsigned short*)(smem + cbase + 8192);
    bf16x8_t a[4], b[4];
    #pragma unroll
    for (int mi = 0; mi < 4; mi++) a[mi] = *reinterpret_cast<const bf16x8_t*>(&As[aoff[mi]]);
    #pragma unroll
    for (int ni = 0; ni < 4; ni++) b[ni] = *reinterpret_cast<const bf16x8_t*>(&Bs[boff[ni]]);
    #pragma unroll
    for (int mi = 0; mi < 4; mi++)
      #pragma unroll
      for (int ni = 0; ni < 4; ni++)
        acc[mi][ni] = __builtin_amdgcn_mfma_f32_16x16x32_bf16(b[ni], a[mi], acc[mi][ni], 0, 0, 0);
    __builtin_amdgcn_s_barrier();
    asm volatile("" ::: "memory");
    cbase += 16384; if (cbase == 49152) cbase = 0;
    sbase += 16384; if (sbase == 49152) sbase = 0;
  }
#undef STAGE
  const bool isQ = (n_blk < 2), isS = (n_blk >= 6);
  if (isQ || isS){
    unsigned short* St = (unsigned short*)smem;   // [64][152] bf16
    unsigned short* outp = isQ ? qbf : sbf;
    const int colhalf = isQ ? n_blk : (n_blk - 6);
    #pragma unroll
    for (int ch = 0; ch < 2; ch++){
      if (wm == ch){
        #pragma unroll
        for (int mi = 0; mi < 4; mi++){
          #pragma unroll
          for (int ni = 0; ni < 4; ni++){
            int mloc = mi * 16 + r;
            int nl = wn * 64 + ni * 16 + q4 * 4;
            float4 bb = *reinterpret_cast<const float4*>(&bcat[n0 + nl]);
            uint2 w;
            w.x = pk2bf(acc[mi][ni][0] + bb.x, acc[mi][ni][1] + bb.y);
            w.y = pk2bf(acc[mi][ni][2] + bb.z, acc[mi][ni][3] + bb.w);
            *reinterpret_cast<uint2*>(&St[mloc * 152 + nl]) = w;
          }
        }
      }
      __syncthreads();
      #pragma unroll
      for (int it = 0; it < 4; it++){
        int u = it * 256 + tid;
        int row = u >> 4, seg = (u & 15) * 8;
        int node = m0 + ch * 64 + row;
        if (node < n_nodes){
          uint4 v = *reinterpret_cast<const uint4*>(&St[row * 152 + seg]);
          *reinterpret_cast<uint4*>(outp + (size_t)node * 256 + colhalf * 128 + seg) = v;
        }
      }
      __syncthreads();
    }
  } else {
    unsigned char* St8 = smem;                    // [64][144] fp8
    #pragma unroll
    for (int ch = 0; ch < 2; ch++){
      if (wm == ch){
        #pragma unroll
        for (int mi = 0; mi < 4; mi++){
          #pragma unroll
          for (int ni = 0; ni < 4; ni++){
            int mloc = mi * 16 + r;
            int nl = wn * 64 + ni * 16 + q4 * 4;
            float4 bb = *reinterpret_cast<const float4*>(&bcat[n0 + nl]);
            int u = 0;
            u = __builtin_amdgcn_cvt_pk_fp8_f32(acc[mi][ni][0] + bb.x, acc[mi][ni][1] + bb.y, u, false);
            u = __builtin_amdgcn_cvt_pk_fp8_f32(acc[mi][ni][2] + bb.z, acc[mi][ni][3] + bb.w, u, true);
            *reinterpret_cast<unsigned int*>(&St8[mloc * 144 + nl]) = (unsigned int)u;
          }
        }
      }
      __syncthreads();
      #pragma unroll
      for (int it = 0; it < 2; it++){
        int u = it * 256 + tid;
        int row = u >> 3, seg = (u & 7) * 16;
        int node = m0 + ch * 64 + row;
        if (node < n_nodes){
          uint4 v = *reinterpret_cast<const uint4*>(&St8[row * 144 + seg]);
          *reinterpret_cast<uint4*>(kv8 + (size_t)node * 512 + (n_blk - 2) * 128 + seg) = v;
        }
      }
      __syncthreads();
    }
  }
}

// ---------------- K7: per-dst online-softmax aggregation
// fp8 K/V (combined 512B row), 16 lanes/edge, 2 chains/node, 2 nodes/wave,
// pair-processing + pair prefetch per chain, shfl_xor(16) merge, fast gelu.
__global__ __launch_bounds__(256) void edge_attn(const unsigned short* __restrict__ qbf,
                                                 const unsigned short* __restrict__ sbf,
                                                 const unsigned char* __restrict__ kv8,
                                                 const int* __restrict__ rowstart,
                                                 const int* __restrict__ csrsrc,
                                                 unsigned short* __restrict__ hbf, int n_nodes){
  const int tid = threadIdx.x;
  const int lane = tid & 63, wave = tid >> 6;
  const int g = lane >> 4, t = lane & 15;
  const int chain = g & 1;
  const int node = blockIdx.x * 8 + wave * 2 + (g >> 1);
  const bool active = node < n_nodes;
  const int nd = active ? node : 0;
  const float qs = 0.0625f * 1.44269504088896340736f;  // (1/sqrt(256)) * log2(e)
  float q[16];
  {
    const unsigned short* qp = qbf + (size_t)nd * 256 + t * 16;
    uint4 w0 = *reinterpret_cast<const uint4*>(qp);
    uint4 w1 = *reinterpret_cast<const uint4*>(qp + 8);
    unp8s(w0, q, qs); unp8s(w1, q + 8, qs);
  }
  int rs = rowstart[nd];
  int re = active ? rowstart[nd + 1] : rs;
  float m = -1e30f, den = 0.f;
  float acc[16];
  #pragma unroll
  for (int j = 0; j < 16; j++) acc[j] = 0.f;
  const int i0 = rs + chain;
  uint4 kA = make_uint4(0,0,0,0), vA = kA, kB = kA, vB = kA;
  if (i0 < re){
    const unsigned char* p1 = kv8 + (size_t)csrsrc[i0] + t * 16;
    kA = *reinterpret_cast<const uint4*>(p1);
    vA = *reinterpret_cast<const uint4*>(p1 + 256);
    if (i0 + 2 < re){
      const unsigned char* p2 = kv8 + (size_t)csrsrc[i0 + 2] + t * 16;
      kB = *reinterpret_cast<const uint4*>(p2);
      vB = *reinterpret_cast<const uint4*>(p2 + 256);
    }
  }
  for (int i = i0; i < re; i += 4){
    uint4 k1 = kA, v1 = vA, k2 = kB, v2 = vB;
    const bool has2 = (i + 2 < re);
    if (i + 4 < re){
      const unsigned char* p1 = kv8 + (size_t)csrsrc[i + 4] + t * 16;
      kA = *reinterpret_cast<const uint4*>(p1);
      vA = *reinterpret_cast<const uint4*>(p1 + 256);
      if (i + 6 < re){
        const unsigned char* p2 = kv8 + (size_t)csrsrc[i + 6] + t * 16;
        kB = *reinterpret_cast<const uint4*>(p2);
        vB = *reinterpret_cast<const uint4*>(p2 + 256);
      }
    }
    float kf1[16], kf2[16];
    unpf8(k1.x, kf1); unpf8(k1.y, kf1 + 4); unpf8(k1.z, kf1 + 8); unpf8(k1.w, kf1 + 12);
    unpf8(k2.x, kf2); unpf8(k2.y, kf2 + 4); unpf8(k2.z, kf2 + 8); unpf8(k2.w, kf2 + 12);
    float s1 = 0.f, s2 = 0.f;
    #pragma unroll
    for (int j = 0; j < 16; j++){ s1 = fmaf(q[j], kf1[j], s1); s2 = fmaf(q[j], kf2[j], s2); }
    s1 += __shfl_xor(s1, 1); s2 += __shfl_xor(s2, 1);
    s1 += __shfl_xor(s1, 2); s2 += __shfl_xor(s2, 2);
    s1 += __shfl_xor(s1, 4); s2 += __shfl_xor(s2, 4);
    s1 += __shfl_xor(s1, 8); s2 += __shfl_xor(s2, 8);
    if (!has2) s2 = -1e30f;
    float vf1[16], vf2[16];
    unpf8(v1.x, vf1); unpf8(v1.y, vf1 + 4); unpf8(v1.z, vf1 + 8); unpf8(v1.w, vf1 + 12);
    unpf8(v2.x, vf2); unpf8(v2.y, vf2 + 4); unpf8(v2.z, vf2 + 8); unpf8(v2.w, vf2 + 12);
    float mn = fmaxf(m, fmaxf(s1, s2));
    float sc = exp2f(m - mn);
    float e1 = exp2f(s1 - mn);
    float e2 = exp2f(s2 - mn);
    den = den * sc + e1 + e2;
    #pragma unroll
    for (int j = 0; j < 16; j++)
      acc[j] = fmaf(acc[j], sc, fmaf(e1, vf1[j], e2 * vf2[j]));
    m = mn;
  }
  // merge the two chains (lane ^ 16 pairs groups 0<->1, 2<->3)
  {
    float mo  = __shfl_xor(m, 16);
    float dno = __shfl_xor(den, 16);
    float mn  = fmaxf(m, mo);
    float a_  = exp2f(m - mn);
    float b_  = exp2f(mo - mn);
    den = den * a_ + dno * b_;
    #pragma unroll
    for (int j = 0; j < 16; j++){
      float oth = __shfl_xor(acc[j], 16);
      acc[j] = acc[j] * a_ + oth * b_;
    }
  }
  float inv = (den > 0.f) ? 1.f / den : 0.f;
  const unsigned short* sp = sbf + (size_t)nd * 256 + t * 16;
  uint4 s0 = *reinterpret_cast<const uint4*>(sp);
  uint4 s1v = *reinterpret_cast<const uint4*>(sp + 8);
  float sf[16]; unp8s(s0, sf, 1.0f); unp8s(s1v, sf + 8, 1.0f);
  unsigned int o[8];
  #pragma unroll
  for (int j = 0; j < 8; j++){
    float h0 = fast_gelu(acc[2 * j] * inv + sf[2 * j]);
    float h1 = fast_gelu(acc[2 * j + 1] * inv + sf[2 * j + 1]);
    o[j] = (unsigned int)f2bf(h0) | ((unsigned int)f2bf(h1) << 16);
  }
  if (active && chain == 0){
    uint4* dst = reinterpret_cast<uint4*>(hbf + (size_t)node * 256 + t * 16);
    dst[0] = make_uint4(o[0], o[1], o[2], o[3]);
    dst[1] = make_uint4(o[4], o[5], o[6], o[7]);
  }
}

// ---------------- K8: es2[n][2] = exp(tanh(hbf@Wa1 + ba1)@Wa2 + ba2); den_g += block sums
__global__ __launch_bounds__(256) void mlp_mfma(const unsigned short* __restrict__ hbf,
                                                const unsigned short* __restrict__ wa1T,
                                                const float* __restrict__ ba1,
                                                const float* __restrict__ Wa2,
                                                const float* __restrict__ ba2,
                                                float* __restrict__ es2,
                                                float* __restrict__ den_g, int n_nodes){
  __shared__ __align__(16) unsigned short As[64 * 72];
  __shared__ float s2s[64][2];
  const int tid = threadIdx.x;
  const int lane = tid & 63, wave = tid >> 6;
  const int m0 = blockIdx.x * 64;
  const int c0 = wave * 64;
  const int r = lane & 15, rg = (lane >> 4) * 4;
  if (tid < 128) s2s[tid >> 1][tid & 1] = 0.f;
  f32x4_t acc[4][4] = {};
  for (int k0 = 0; k0 < 256; k0 += 64){
    int arow = tid >> 2, akc = (tid & 3) * 16;
    uint4 a0v = make_uint4(0,0,0,0), a1v = make_uint4(0,0,0,0);
    if (m0 + arow < n_nodes){
      const unsigned short* src = hbf + (size_t)(m0 + arow) * 256 + k0 + akc;
      a0v = *reinterpret_cast<const uint4*>(src);
      a1v = *reinterpret_cast<const uint4*>(src + 8);
    }
    *reinterpret_cast<uint4*>(&As[arow * 72 + akc]) = a0v;
    *reinterpret_cast<uint4*>(&As[arow * 72 + akc + 8]) = a1v;
    __syncthreads();
    #pragma unroll
    for (int kk = 0; kk < 2; kk++){
      int kg = kk * 32 + (lane >> 4) * 8;
      bf16x8_t a[4], b[4];
      #pragma unroll
      for (int mi = 0; mi < 4; mi++)
        a[mi] = *reinterpret_cast<const bf16x8_t*>(&As[(mi * 16 + r) * 72 + kg]);
      #pragma unroll
      for (int ni = 0; ni < 4; ni++)
        b[ni] = *reinterpret_cast<const bf16x8_t*>(wa1T + (size_t)(c0 + ni * 16 + r) * 256 + k0 + kg);
      #pragma unroll
      for (int mi = 0; mi < 4; mi++)
        #pragma unroll
        for (int ni = 0; ni < 4; ni++)
          acc[mi][ni] = __builtin_amdgcn_mfma_f32_16x16x32_bf16(a[mi], b[ni], acc[mi][ni], 0, 0, 0);
    }
    __syncthreads();
  }
  float w20[4], w21[4], b1c[4];
  #pragma unroll
  for (int ni = 0; ni < 4; ni++){
    int col = c0 + ni * 16 + r;
    w20[ni] = Wa2[col * 2]; w21[ni] = Wa2[col * 2 + 1]; b1c[ni] = ba1[col];
  }
  #pragma unroll
  for (int mi = 0; mi < 4; mi++){
    #pragma unroll
    for (int j = 0; j < 4; j++){
      float t0 = 0.f, t1 = 0.f;
      #pragma unroll
      for (int ni = 0; ni < 4; ni++){
        float t = fast_tanh(acc[mi][ni][j] + b1c[ni]);
        t0 += t * w20[ni]; t1 += t * w21[ni];
      }
      t0 += __shfl_xor(t0, 1); t0 += __shfl_xor(t0, 2);
      t0 += __shfl_xor(t0, 4); t0 += __shfl_xor(t0, 8);
      t1 += __shfl_xor(t1, 1); t1 += __shfl_xor(t1, 2);
      t1 += __shfl_xor(t1, 4); t1 += __shfl_xor(t1, 8);
      if (r == 0){
        int row = mi * 16 + rg + j;
        atomicAdd(&s2s[row][0], t0);
        atomicAdd(&s2s[row][1], t1);
      }
    }
  }
  __syncthreads();
  if (tid < 128){
    int row = tid >> 1, c = tid & 1;
    int node = m0 + row;
    float e = 0.f;
    if (node < n_nodes){
      e = expf(s2s[row][c] + ba2[c]);
      es2[node * 2 + c] = e;
    }
    float sum = e;
    sum += __shfl_xor(sum, 2);  sum += __shfl_xor(sum, 4);
    sum += __shfl_xor(sum, 8);  sum += __shfl_xor(sum, 16);
    sum += __shfl_xor(sum, 32);
    if ((tid & 63) < 2) atomicAdd(&den_g[c], sum);
  }
}

// ---------------- K10: attn + A output + M accumulation + fused logits (completion counter)
__global__ __launch_bounds__(256) void attn_M(const float* __restrict__ es2, const float* __restrict__ den_g,
                                              const unsigned short* __restrict__ hbf, const int* __restrict__ label,
                                              float* __restrict__ Mbuf, float* __restrict__ outA,
                                              const float* __restrict__ Wc, const float* __restrict__ bc,
                                              float* __restrict__ out, unsigned int* __restrict__ cnt,
                                              int n, int nblocks){
  __shared__ float a0s[256], a1s[256];
  __shared__ float Ms[512];
  __shared__ unsigned int lastrank;
  int tid = threadIdx.x;
  int n0 = blockIdx.x * 256;
  int node = n0 + tid;
  float i0 = 1.f / den_g[0], i1 = 1.f / den_g[1];
  float a0 = 0.f, a1 = 0.f;
  if (node < n){
    a0 = es2[2 * node] * i0;
    a1 = es2[2 * node + 1] * i1;
    outA[node] = (label[0] == 0) ? a0 : a1;
  }
  a0s[tid] = a0; a1s[tid] = a1;
  Ms[tid] = 0.f; Ms[tid + 256] = 0.f;
  __syncthreads();
  const int dgrp = tid & 31;
  const int nl = tid >> 5;
  float M0[8] = {}, M1[8] = {};
  for (int i = nl; i < 256; i += 8){
    int nd = n0 + i;
    if (nd >= n) break;
    uint4 w = *reinterpret_cast<const uint4*>(hbf + (size_t)nd * 256 + dgrp * 8);
    float f[8]; unp8s(w, f, 1.0f);
    float A0 = a0s[i], A1 = a1s[i];
    #pragma unroll
    for (int j = 0; j < 8; j++){
      M0[j] = fmaf(A0, f[j], M0[j]);
      M1[j] = fmaf(A1, f[j], M1[j]);
    }
  }
  #pragma unroll
  for (int j = 0; j < 8; j++){
    M0[j] += __shfl_xor(M0[j], 32);
    M1[j] += __shfl_xor(M1[j], 32);
  }
  if ((tid & 32) == 0){
    #pragma unroll
    for (int j = 0; j < 8; j++){
      atomicAdd(&Ms[dgrp * 8 + j], M0[j]);
      atomicAdd(&Ms[256 + dgrp * 8 + j], M1[j]);
    }
  }
  __syncthreads();
  atomicAdd(&Mbuf[tid], Ms[tid]);
  atomicAdd(&Mbuf[256 + tid], Ms[tid + 256]);
  __threadfence();
  if (tid == 0) lastrank = atomicAdd(cnt, 1u);
  __syncthreads();
  if (lastrank == (unsigned int)(nblocks - 1)){
    float m0v = __hip_atomic_load(&Mbuf[tid], __ATOMIC_RELAXED, __HIP_MEMORY_SCOPE_AGENT);
    float m1v = __hip_atomic_load(&Mbuf[256 + tid], __ATOMIC_RELAXED, __HIP_MEMORY_SCOPE_AGENT);
    a0s[tid] = m0v * Wc[tid];
    a1s[tid] = m1v * Wc[256 + tid];
    __syncthreads();
    for (int off = 128; off > 0; off >>= 1){
      if (tid < off){ a0s[tid] += a0s[tid + off]; a1s[tid] += a1s[tid + off]; }
      __syncthreads();
    }
    if (tid == 0){
      float l0 = a0s[0] + bc[0];
      float l1 = a1s[0] + bc[1];
      out[0] = l0; out[1] = l1;
      float mx = fmaxf(l0, l1);
      float e0 = expf(l0 - mx), e1 = expf(l1 - mx);
      float inv = 1.f / (e0 + e1);
      out[2] = e0 * inv; out[3] = e1 * inv;
    }
  }
}

extern "C" void kernel_launch(void* const* d_in, const int* in_sizes, int n_in,
                              void* d_out, int out_size, void* d_ws, size_t ws_size,
                              hipStream_t stream) {
  const float* x   = (const float*)d_in[0];
  const int*   ei  = (const int*)d_in[1];
  const int*   lab = (const int*)d_in[2];
  const float* Wq  = (const float*)d_in[3];
  const float* bq  = (const float*)d_in[4];
  const float* Wk  = (const float*)d_in[5];
  const float* bk  = (const float*)d_in[6];
  const float* Wv  = (const float*)d_in[7];
  const float* bv  = (const float*)d_in[8];
  const float* Ws  = (const float*)d_in[9];
  const float* bs  = (const float*)d_in[10];
  const float* Wa1 = (const float*)d_in[11];
  const float* ba1 = (const float*)d_in[12];
  const float* Wa2 = (const float*)d_in[13];
  const float* ba2 = (const float*)d_in[14];
  const float* Wc  = (const float*)d_in[15];
  const float* bc  = (const float*)d_in[16];
  float* out = (float*)d_out;

  const int n  = in_sizes[0] / 512;   // 20000
  const int ne = in_sizes[1] / 2;     // 320000

  char* ws = (char*)d_ws;
  size_t off = 0;
  auto take = [&](size_t bytes){ size_t r = off; off += (bytes + 255) & ~(size_t)255; return r; };
  unsigned short* wcatT  = (unsigned short*)(ws + take((size_t)1024 * 512 * 2));
  float*          bcat   = (float*)(ws + take(1024 * 4));
  unsigned short* xbf    = (unsigned short*)(ws + take((size_t)n * 512 * 2));
  unsigned short* qbf    = (unsigned short*)(ws + take((size_t)n * 256 * 2));
  unsigned short* sbf    = (unsigned short*)(ws + take((size_t)n * 256 * 2));
  unsigned char*  kv8    = (unsigned char*)(ws + take((size_t)n * 512));
  unsigned short* hbf    = (unsigned short*)(ws + take((size_t)n * 256 * 2));
  unsigned short* wa1T   = (unsigned short*)(ws + take((size_t)256 * 256 * 2));
  float*          es2    = (float*)(ws + take((size_t)n * 2 * 4));
  size_t zoff = off;
  int*            deg    = (int*)(ws + take((size_t)n * 4));
  int*            cursor = (int*)(ws + take((size_t)n * 4));
  float*          Mbuf   = (float*)(ws + take(512 * 4));
  float*          den_g  = (float*)(ws + take(2 * 4));
  unsigned int*   cnt    = (unsigned int*)(ws + take(4));
  size_t zlen = off - zoff;
  int*            rowst  = (int*)(ws + take((size_t)(n + 1) * 4));
  int*            csrsrc = (int*)(ws + take((size_t)ne * 4));

  const int z16 = (int)(zlen / 16);
  zero_buf<<<(z16 + 255) / 256, 256, 0, stream>>>((uint4*)(ws + zoff), z16);

  const int nbcv = (n * 64 + 255) / 256;
  const int nbdh = (ne + 255) / 256;
  prep<<<2304 + nbcv + nbdh, 256, 0, stream>>>(x, Wq, Wk, Wv, Ws, bq, bk, bv, bs, Wa1, ei,
                                               xbf, wcatT, bcat, wa1T, deg, n, ne, nbcv);
  scan_deg<<<1, 1024, 0, stream>>>(deg, rowst, n, ne);
  const int mblocks = (n + 127) / 128;
  const int ngemm = 8 * mblocks;
  const int nscb = (ne + 255) / 256;
  gemm_qkvs<<<ngemm + nscb, 256, 0, stream>>>(xbf, wcatT, bcat, qbf, sbf, kv8,
                                              ei, rowst, cursor, csrsrc, n, ne, mblocks, ngemm);
  edge_attn<<<(n + 7) / 8, 256, 0, stream>>>(qbf, sbf, kv8, rowst, csrsrc, hbf, n);
  mlp_mfma<<<(n + 63) / 64, 256, 0, stream>>>(hbf, wa1T, ba1, Wa2, ba2, es2, den_g, n);
  const int nbam = (n + 255) / 256;
  attn_M<<<nbam, 256, 0, stream>>>(es2, den_g, hbf, lab, Mbuf, out + 4, Wc, bc, out, cnt, n, nbam);
  (void)ws_size; (void)out_size; (void)n_in;
}